// Round 1
// baseline (1866.346 us; speedup 1.0000x reference)
//
#include <hip/hip_runtime.h>
#include <math.h>

// ---------------------------------------------------------------------------
// Problem constants (from reference)
// ---------------------------------------------------------------------------
#define NN 50000          // nodes
#define NE 800000         // edges (before self loops)
#define NEP (NE + NN)     // edges incl self loops
#define NGR 64            // graphs
#define NHEAD 8

// ---------------------------------------------------------------------------
// CSR build kernels (dst-major). Edge e<NE: src=ei[e], dst=ei[NE+e]; else self.
// ---------------------------------------------------------------------------
__global__ void count_deg(const int* __restrict__ ei, int* __restrict__ deg) {
    int e = blockIdx.x * 256 + threadIdx.x;
    if (e >= NEP) return;
    int d = (e < NE) ? ei[NE + e] : (e - NE);
    atomicAdd(&deg[d], 1);
}

__global__ void scan_kernel(const int* __restrict__ deg, int* __restrict__ row_ptr, int n) {
    __shared__ int sd[1024];
    __shared__ int soff;
    int t = threadIdx.x;
    if (t == 0) soff = 0;
    __syncthreads();
    for (int base = 0; base < n; base += 1024) {
        int i = base + t;
        int v = (i < n) ? deg[i] : 0;
        sd[t] = v;
        __syncthreads();
        for (int off = 1; off < 1024; off <<= 1) {
            int tmp = (t >= off) ? sd[t - off] : 0;
            __syncthreads();
            sd[t] += tmp;
            __syncthreads();
        }
        int off0 = soff;
        int incl = sd[t];
        if (i < n) row_ptr[i] = off0 + incl - v;   // exclusive
        __syncthreads();
        if (t == 1023) soff = off0 + sd[1023];
        __syncthreads();
    }
    if (t == 0) row_ptr[n] = soff;
}

__global__ void copy_int(const int* __restrict__ a, int* __restrict__ b, int n) {
    int i = blockIdx.x * 256 + threadIdx.x;
    if (i < n) b[i] = a[i];
}

__global__ void scatter_edges(const int* __restrict__ ei, int* __restrict__ cursor,
                              int* __restrict__ srcs) {
    int e = blockIdx.x * 256 + threadIdx.x;
    if (e >= NEP) return;
    int s, d;
    if (e < NE) { s = ei[e]; d = ei[NE + e]; }
    else        { s = e - NE; d = e - NE; }
    int pos = atomicAdd(&cursor[d], 1);
    srcs[pos] = s;
}

// ---------------------------------------------------------------------------
// fp32 GEMM: C[M,Nc] = A[M,K] * B[Nc,K]^T   (both row-major, K contiguous)
// 128x128 block tile, 8x8 per thread, BK=16. M arbitrary, Nc%128==0, K%16==0.
// ---------------------------------------------------------------------------
#define BM 128
#define BN 128
#define BK 16
__global__ __launch_bounds__(256) void gemm_nt(const float* __restrict__ A,
                                               const float* __restrict__ B,
                                               float* __restrict__ C,
                                               int M, int Nc, int K, int colTiles) {
    __shared__ float As[BK][BM + 8];
    __shared__ float Bs[BK][BN + 8];
    int bx = blockIdx.x % colTiles;
    int by = blockIdx.x / colTiles;
    int row0 = by * BM;
    int col0 = bx * BN;
    int t = threadIdx.x;
    int tx = t % 16, ty = t / 16;

    float acc[8][8];
#pragma unroll
    for (int i = 0; i < 8; i++)
#pragma unroll
        for (int j = 0; j < 8; j++) acc[i][j] = 0.f;

    for (int k0 = 0; k0 < K; k0 += BK) {
#pragma unroll
        for (int i = 0; i < 2; i++) {
            int f = t + i * 256;          // 0..511
            int r = f >> 2;               // row within tile
            int kc = (f & 3) * 4;         // k sub-chunk
            int gr = row0 + r;
            float4 v = make_float4(0.f, 0.f, 0.f, 0.f);
            if (gr < M) v = *(const float4*)(A + (size_t)gr * K + k0 + kc);
            As[kc + 0][r] = v.x; As[kc + 1][r] = v.y;
            As[kc + 2][r] = v.z; As[kc + 3][r] = v.w;
        }
#pragma unroll
        for (int i = 0; i < 2; i++) {
            int f = t + i * 256;
            int r = f >> 2;
            int kc = (f & 3) * 4;
            int gc = col0 + r;            // always < Nc (Nc % 128 == 0)
            float4 v = *(const float4*)(B + (size_t)gc * K + k0 + kc);
            Bs[kc + 0][r] = v.x; Bs[kc + 1][r] = v.y;
            Bs[kc + 2][r] = v.z; Bs[kc + 3][r] = v.w;
        }
        __syncthreads();
#pragma unroll
        for (int kk = 0; kk < BK; kk++) {
            float4 a0 = *(const float4*)&As[kk][ty * 8];
            float4 a1 = *(const float4*)&As[kk][ty * 8 + 4];
            float4 b0 = *(const float4*)&Bs[kk][tx * 8];
            float4 b1 = *(const float4*)&Bs[kk][tx * 8 + 4];
            float av[8] = {a0.x, a0.y, a0.z, a0.w, a1.x, a1.y, a1.z, a1.w};
            float bv[8] = {b0.x, b0.y, b0.z, b0.w, b1.x, b1.y, b1.z, b1.w};
#pragma unroll
            for (int i = 0; i < 8; i++)
#pragma unroll
                for (int j = 0; j < 8; j++) acc[i][j] = fmaf(av[i], bv[j], acc[i][j]);
        }
        __syncthreads();
    }
#pragma unroll
    for (int i = 0; i < 8; i++) {
        int gr = row0 + ty * 8 + i;
        if (gr >= M) continue;
#pragma unroll
        for (int j = 0; j < 8; j += 4) {
            float4 v = make_float4(acc[i][j], acc[i][j + 1], acc[i][j + 2], acc[i][j + 3]);
            *(float4*)(C + (size_t)gr * Nc + col0 + tx * 8 + j) = v;
        }
    }
}

// ---------------------------------------------------------------------------
// es/ed: per (node, head) dot over C channels.
// ---------------------------------------------------------------------------
template <int C>
__global__ void compute_esed(const float* __restrict__ h, const float* __restrict__ a_s,
                             const float* __restrict__ a_d, float* __restrict__ es,
                             float* __restrict__ ed) {
    int gid = blockIdx.x * 256 + threadIdx.x;
    if (gid >= NN * NHEAD) return;
    int n = gid >> 3, hh = gid & 7;
    const float* hr = h + (size_t)n * NHEAD * C + hh * C;
    const float* as = a_s + hh * C;
    const float* ad = a_d + hh * C;
    float s1 = 0.f, s2 = 0.f;
#pragma unroll 4
    for (int c = 0; c < C; c += 4) {
        float4 hv = *(const float4*)(hr + c);
        float4 av = *(const float4*)(as + c);
        float4 dv = *(const float4*)(ad + c);
        s1 += hv.x * av.x + hv.y * av.y + hv.z * av.z + hv.w * av.w;
        s2 += hv.x * dv.x + hv.y * dv.y + hv.z * dv.z + hv.w * dv.w;
    }
    es[gid] = s1;
    ed[gid] = s2;
}

// ---------------------------------------------------------------------------
// Attention softmax + aggregation, one block per dst node, CSR, no atomics.
// Writes out = aggregate + bias, optional ELU.
// ---------------------------------------------------------------------------
#define DEG_CAP 512
template <int C, bool ELU>
__global__ __launch_bounds__(256) void attn_agg(const float* __restrict__ h,
                                                const float* __restrict__ es,
                                                const float* __restrict__ ed,
                                                const int* __restrict__ row_ptr,
                                                const int* __restrict__ srcs,
                                                const float* __restrict__ bias,
                                                float* __restrict__ out) {
    constexpr int HC = NHEAD * C;
    __shared__ float lw[DEG_CAP * NHEAD];
    __shared__ float red[256];
    __shared__ float sm_max[NHEAD];
    __shared__ float sm_den[NHEAD];

    int n = blockIdx.x;
    int start = row_ptr[n];
    int deg = row_ptr[n + 1] - start;
    int t = threadIdx.x;
    float edv = ed[n * NHEAD + (t & 7)];

    // phase 1: per-head max of leaky_relu(es[src]+ed[n])
    float pm = -1e30f;
    for (int idx = t; idx < deg * NHEAD; idx += 256) {
        int k = idx >> 3, hh = idx & 7;
        int s = srcs[start + k];
        float e = es[s * NHEAD + hh] + edv;
        e = e > 0.f ? e : 0.2f * e;
        pm = fmaxf(pm, e);
    }
    red[t] = pm;
    __syncthreads();
    for (int off = 128; off >= 8; off >>= 1) {
        if (t < off) red[t] = fmaxf(red[t], red[t + off]);
        __syncthreads();
    }
    if (t < NHEAD) sm_max[t] = red[t];
    __syncthreads();

    // phase 2: sum of exp(e - max), stash weights in LDS
    float mh = sm_max[t & 7];
    float ps = 0.f;
    for (int idx = t; idx < deg * NHEAD; idx += 256) {
        int k = idx >> 3, hh = idx & 7;
        int s = srcs[start + k];
        float e = es[s * NHEAD + hh] + edv;
        e = e > 0.f ? e : 0.2f * e;
        float w = __expf(e - mh);
        if (k < DEG_CAP) lw[idx] = w;
        ps += w;
    }
    red[t] = ps;
    __syncthreads();
    for (int off = 128; off >= 8; off >>= 1) {
        if (t < off) red[t] += red[t + off];
        __syncthreads();
    }
    if (t < NHEAD) sm_den[t] = red[t];
    __syncthreads();

    // normalize stored weights
    int degc = deg < DEG_CAP ? deg : DEG_CAP;
    float invd = 1.0f / sm_den[t & 7];
    for (int idx = t; idx < degc * NHEAD; idx += 256) lw[idx] *= invd;
    __syncthreads();

    // phase 3: out[n,c] = sum_k alpha[k,head(c)] * h[src_k, c]  (+bias, ELU)
    for (int c = t; c < HC; c += 256) {
        int hh = c / C;
        float acc = 0.f;
        for (int k = 0; k < degc; k++) {
            int s = srcs[start + k];
            acc = fmaf(lw[k * NHEAD + hh], h[(size_t)s * HC + c], acc);
        }
        if (deg > DEG_CAP) {   // robust fallback, never taken for this graph
            float mhh = sm_max[hh];
            float dinvh = 1.0f / sm_den[hh];
            for (int k = DEG_CAP; k < deg; k++) {
                int s = srcs[start + k];
                float e = es[s * NHEAD + hh] + ed[n * NHEAD + hh];
                e = e > 0.f ? e : 0.2f * e;
                acc = fmaf(__expf(e - mhh) * dinvh, h[(size_t)s * HC + c], acc);
            }
        }
        float o = acc + bias[c];
        if (ELU) o = o > 0.f ? o : (__expf(o) - 1.0f);
        out[(size_t)n * HC + c] = o;
    }
}

// ---------------------------------------------------------------------------
// Global mean pool (batch sorted), one block per graph, 512 features.
// ---------------------------------------------------------------------------
__global__ __launch_bounds__(256) void pool_kernel(const float* __restrict__ h,
                                                   const int* __restrict__ batch,
                                                   float* __restrict__ gout) {
    int g = blockIdx.x;
    int lo = 0, hi = NN;
    while (lo < hi) { int mid = (lo + hi) >> 1; if (batch[mid] < g) lo = mid + 1; else hi = mid; }
    int s = lo;
    lo = 0; hi = NN;
    while (lo < hi) { int mid = (lo + hi) >> 1; if (batch[mid] < g + 1) lo = mid + 1; else hi = mid; }
    int e = lo;
    int t = threadIdx.x;
    float a0 = 0.f, a1 = 0.f;
    for (int r = s; r < e; r++) {
        a0 += h[(size_t)r * 512 + t];
        a1 += h[(size_t)r * 512 + 256 + t];
    }
    float inv = 1.0f / fmaxf((float)(e - s), 1.0f);
    gout[g * 512 + t] = a0 * inv;
    gout[g * 512 + 256 + t] = a1 * inv;
}

// ---------------------------------------------------------------------------
// Final MLP: [64,512] -> elu(@lw1^T+lb1) [64,32] -> @lw2^T+lb2 [64,2]
// ---------------------------------------------------------------------------
__global__ __launch_bounds__(64) void mlp_kernel(const float* __restrict__ g,
                                                 const float* __restrict__ lw1,
                                                 const float* __restrict__ lb1,
                                                 const float* __restrict__ lw2,
                                                 const float* __restrict__ lb2,
                                                 float* __restrict__ outp) {
    __shared__ float gv[512];
    __shared__ float y1[32];
    int b = blockIdx.x, t = threadIdx.x;
    for (int i = t; i < 512; i += 64) gv[i] = g[b * 512 + i];
    __syncthreads();
    if (t < 32) {
        float a = lb1[t];
        for (int k = 0; k < 512; k++) a = fmaf(gv[k], lw1[t * 512 + k], a);
        y1[t] = a > 0.f ? a : (__expf(a) - 1.0f);
    }
    __syncthreads();
    if (t < 2) {
        float a = lb2[t];
        for (int k = 0; k < 32; k++) a = fmaf(y1[k], lw2[t * 32 + k], a);
        outp[b * 2 + t] = a;
    }
}

// ---------------------------------------------------------------------------
// Launch
// ---------------------------------------------------------------------------
extern "C" void kernel_launch(void* const* d_in, const int* in_sizes, int n_in,
                              void* d_out, int out_size, void* d_ws, size_t ws_size,
                              hipStream_t stream) {
    (void)in_sizes; (void)n_in; (void)out_size; (void)ws_size;
    const float* x     = (const float*)d_in[0];
    const int*   ei    = (const int*)d_in[1];
    const int*   batch = (const int*)d_in[2];
    const float* W[4]  = {(const float*)d_in[3], (const float*)d_in[7],
                          (const float*)d_in[11], (const float*)d_in[15]};
    const float* As_[4] = {(const float*)d_in[4], (const float*)d_in[8],
                           (const float*)d_in[12], (const float*)d_in[16]};
    const float* Ad_[4] = {(const float*)d_in[5], (const float*)d_in[9],
                           (const float*)d_in[13], (const float*)d_in[17]};
    const float* Bi[4]  = {(const float*)d_in[6], (const float*)d_in[10],
                           (const float*)d_in[14], (const float*)d_in[18]};
    const float* lw1 = (const float*)d_in[19];
    const float* lb1 = (const float*)d_in[20];
    const float* lw2 = (const float*)d_in[21];
    const float* lb2 = (const float*)d_in[22];
    float* out = (float*)d_out;

    // workspace layout
    float* B0   = (float*)d_ws;                 // h buffer      [NN*512]
    float* B1   = B0 + (size_t)NN * 512;        // act buffer    [NN*512]
    float* esb  = B1 + (size_t)NN * 512;        // [NN*8]
    float* edb  = esb + NN * NHEAD;             // [NN*8]
    float* gbuf = edb + NN * NHEAD;             // [64*512]
    int* row_ptr = (int*)(gbuf + NGR * 512);    // [NN+1]
    int* cursor  = row_ptr + (NN + 1);          // [NN+1]
    int* srcs    = cursor + (NN + 1);           // [NEP]

    // ---- CSR build (shared by all 4 layers)
    hipMemsetAsync(cursor, 0, NN * sizeof(int), stream);
    count_deg<<<(NEP + 255) / 256, 256, 0, stream>>>(ei, cursor);
    scan_kernel<<<1, 1024, 0, stream>>>(cursor, row_ptr, NN);
    copy_int<<<(NN + 255) / 256, 256, 0, stream>>>(row_ptr, cursor, NN);
    scatter_edges<<<(NEP + 255) / 256, 256, 0, stream>>>(ei, cursor, srcs);

    const int rowTiles = (NN + BM - 1) / BM;    // 391
    int eg = (NN * NHEAD + 255) / 256;

    // ---- layer 1: 128 -> 512 (H=8, C=64), ELU
    gemm_nt<<<rowTiles * 4, 256, 0, stream>>>(x, W[0], B0, NN, 512, 128, 4);
    compute_esed<64><<<eg, 256, 0, stream>>>(B0, As_[0], Ad_[0], esb, edb);
    attn_agg<64, true><<<NN, 256, 0, stream>>>(B0, esb, edb, row_ptr, srcs, Bi[0], B1);

    // ---- layer 2: 512 -> 256 (C=32), ELU
    gemm_nt<<<rowTiles * 2, 256, 0, stream>>>(B1, W[1], B0, NN, 256, 512, 2);
    compute_esed<32><<<eg, 256, 0, stream>>>(B0, As_[1], Ad_[1], esb, edb);
    attn_agg<32, true><<<NN, 256, 0, stream>>>(B0, esb, edb, row_ptr, srcs, Bi[1], B1);

    // ---- layer 3: 256 -> 128 (C=16), ELU
    gemm_nt<<<rowTiles * 1, 256, 0, stream>>>(B1, W[2], B0, NN, 128, 256, 1);
    compute_esed<16><<<eg, 256, 0, stream>>>(B0, As_[2], Ad_[2], esb, edb);
    attn_agg<16, true><<<NN, 256, 0, stream>>>(B0, esb, edb, row_ptr, srcs, Bi[2], B1);

    // ---- layer 4: 128 -> 512 (C=64), no ELU
    gemm_nt<<<rowTiles * 4, 256, 0, stream>>>(B1, W[3], B0, NN, 512, 128, 4);
    compute_esed<64><<<eg, 256, 0, stream>>>(B0, As_[3], Ad_[3], esb, edb);
    attn_agg<64, false><<<NN, 256, 0, stream>>>(B0, esb, edb, row_ptr, srcs, Bi[3], B1);

    // ---- pool + MLP
    pool_kernel<<<NGR, 256, 0, stream>>>(B1, batch, gbuf);
    mlp_kernel<<<NGR, 64, 0, stream>>>(gbuf, lw1, lb1, lw2, lb2, out);
}

// Round 2
// 1360.834 us; speedup vs baseline: 1.3715x; 1.3715x over previous
//
#include <hip/hip_runtime.h>
#include <math.h>

// ---------------------------------------------------------------------------
// Problem constants
// ---------------------------------------------------------------------------
#define NN 50000          // nodes
#define NE 800000         // edges (before self loops)
#define NEP (NE + NN)     // edges incl self loops
#define NGR 64            // graphs
#define NHEAD 8
#define MPAD 50048        // 391 * 128

typedef short short8 __attribute__((ext_vector_type(8)));
typedef float floatx4 __attribute__((ext_vector_type(4)));

__device__ inline float bf2f(short s) {
    union { unsigned u; float f; } v;
    v.u = ((unsigned)(unsigned short)s) << 16;
    return v.f;
}
__device__ inline short f2bf(float f) {
    union { float f; unsigned u; } v; v.f = f;
    unsigned r = v.u + 0x7fffu + ((v.u >> 16) & 1u);   // RNE
    return (short)(r >> 16);
}

// ---------------------------------------------------------------------------
// CSR build (dst-major). Edge e<NE: src=ei[e], dst=ei[NE+e]; else self loop.
// ---------------------------------------------------------------------------
__global__ void count_deg(const int* __restrict__ ei, int* __restrict__ deg) {
    int e = blockIdx.x * 256 + threadIdx.x;
    if (e >= NEP) return;
    int d = (e < NE) ? ei[NE + e] : (e - NE);
    atomicAdd(&deg[d], 1);
}

__global__ void scan_kernel(const int* __restrict__ deg, int* __restrict__ row_ptr, int n) {
    __shared__ int sd[1024];
    __shared__ int soff;
    int t = threadIdx.x;
    if (t == 0) soff = 0;
    __syncthreads();
    for (int base = 0; base < n; base += 1024) {
        int i = base + t;
        int v = (i < n) ? deg[i] : 0;
        sd[t] = v;
        __syncthreads();
        for (int off = 1; off < 1024; off <<= 1) {
            int tmp = (t >= off) ? sd[t - off] : 0;
            __syncthreads();
            sd[t] += tmp;
            __syncthreads();
        }
        int off0 = soff;
        if (i < n) row_ptr[i] = off0 + sd[t] - v;   // exclusive
        __syncthreads();
        if (t == 1023) soff = off0 + sd[1023];
        __syncthreads();
    }
    if (t == 0) row_ptr[n] = soff;
}

__global__ void copy_int(const int* __restrict__ a, int* __restrict__ b, int n) {
    int i = blockIdx.x * 256 + threadIdx.x;
    if (i < n) b[i] = a[i];
}

__global__ void scatter_edges(const int* __restrict__ ei, int* __restrict__ cursor,
                              int* __restrict__ srcs) {
    int e = blockIdx.x * 256 + threadIdx.x;
    if (e >= NEP) return;
    int s, d;
    if (e < NE) { s = ei[e]; d = ei[NE + e]; }
    else        { s = e - NE; d = e - NE; }
    int pos = atomicAdd(&cursor[d], 1);
    srcs[pos] = s;
}

// ---------------------------------------------------------------------------
// fp32 -> bf16 conversions
// ---------------------------------------------------------------------------
__global__ void conv_f2bf(const float* __restrict__ in, short* __restrict__ out, int n) {
    int i = blockIdx.x * 256 + threadIdx.x;
    if (i < n) out[i] = f2bf(in[i]);
}

__global__ void conv_x_pad(const float* __restrict__ x, short* __restrict__ xb) {
    int i = blockIdx.x * 256 + threadIdx.x;
    if (i >= MPAD * 128) return;
    int r = i >> 7;
    xb[i] = (r < NN) ? f2bf(x[i]) : (short)0;
}

// ---------------------------------------------------------------------------
// bf16 MFMA GEMM: C[MPAD,Nc](bf16) = A[MPAD,K](bf16) @ B[Nc,K](bf16)^T
// 128x128 tile, BK=32, 4 waves, each wave 64x64 via 4x4 mfma_16x16x32_bf16.
// K%32==0, Nc%128==0, rows padded to MPAD (multiple of 128) -> no guards.
// ---------------------------------------------------------------------------
#define LDA 48   // padded LDS row stride in shorts (32 + 16 -> 4-way max conflict)
__global__ __launch_bounds__(256) void gemm_bf(const short* __restrict__ A,
                                               const short* __restrict__ B,
                                               short* __restrict__ C,
                                               int K, int Nc, int colTiles) {
    __shared__ __align__(16) short As[128 * LDA];
    __shared__ __align__(16) short Bs[128 * LDA];
    int bx = blockIdx.x % colTiles;
    int by = blockIdx.x / colTiles;
    int row0 = by * 128, col0 = bx * 128;
    int t = threadIdx.x;
    int lane = t & 63, w = t >> 6;
    int wr = (w >> 1) * 64, wc = (w & 1) * 64;
    int lrow = lane & 15, lq = lane >> 4;

    floatx4 acc[4][4];
#pragma unroll
    for (int i = 0; i < 4; i++)
#pragma unroll
        for (int j = 0; j < 4; j++) acc[i][j] = (floatx4)0.0f;

    for (int k0 = 0; k0 < K; k0 += 32) {
#pragma unroll
        for (int i = 0; i < 2; i++) {
            int chunk = t + i * 256;          // 0..511
            int r = chunk >> 2;
            int kc = (chunk & 3) * 8;
            *(short8*)&As[r * LDA + kc] = *(const short8*)&A[(size_t)(row0 + r) * K + k0 + kc];
            *(short8*)&Bs[r * LDA + kc] = *(const short8*)&B[(size_t)(col0 + r) * K + k0 + kc];
        }
        __syncthreads();
        short8 af[4], bfr[4];
#pragma unroll
        for (int i = 0; i < 4; i++)
            af[i] = *(const short8*)&As[(wr + i * 16 + lrow) * LDA + lq * 8];
#pragma unroll
        for (int j = 0; j < 4; j++)
            bfr[j] = *(const short8*)&Bs[(wc + j * 16 + lrow) * LDA + lq * 8];
#pragma unroll
        for (int i = 0; i < 4; i++)
#pragma unroll
            for (int j = 0; j < 4; j++)
                acc[i][j] = __builtin_amdgcn_mfma_f32_16x16x32_bf16(af[i], bfr[j], acc[i][j], 0, 0, 0);
        __syncthreads();
    }
    // epilogue: D row=(lq*4+r) within 16-tile (A/m side), col=lrow (B/n side)
#pragma unroll
    for (int i = 0; i < 4; i++)
#pragma unroll
        for (int j = 0; j < 4; j++)
#pragma unroll
            for (int r = 0; r < 4; r++) {
                int row = row0 + wr + i * 16 + lq * 4 + r;
                int col = col0 + wc + j * 16 + lrow;
                C[(size_t)row * Nc + col] = f2bf(acc[i][j][r]);
            }
}

// ---------------------------------------------------------------------------
// es/ed: per (node, head) dot over C channels (h bf16, a fp32).
// ---------------------------------------------------------------------------
template <int C>
__global__ void compute_esed(const short* __restrict__ h, const float* __restrict__ a_s,
                             const float* __restrict__ a_d, float* __restrict__ es,
                             float* __restrict__ ed) {
    int gid = blockIdx.x * 256 + threadIdx.x;
    if (gid >= NN * NHEAD) return;
    int n = gid >> 3, hh = gid & 7;
    const short* hr = h + (size_t)n * NHEAD * C + hh * C;
    const float* as = a_s + hh * C;
    const float* ad = a_d + hh * C;
    float s1 = 0.f, s2 = 0.f;
#pragma unroll
    for (int c = 0; c < C; c += 8) {
        short8 hv = *(const short8*)&hr[c];
#pragma unroll
        for (int j = 0; j < 8; j++) {
            float hvf = bf2f(hv[j]);
            s1 = fmaf(hvf, as[c + j], s1);
            s2 = fmaf(hvf, ad[c + j], s2);
        }
    }
    es[gid] = s1;
    ed[gid] = s2;
}

// ---------------------------------------------------------------------------
// Attention softmax + aggregation, one block per dst node, CSR, no atomics.
// h bf16 in, out bf16 (= next layer act), fp32 accumulation.
// ---------------------------------------------------------------------------
#define DEG_CAP 256
template <int C, bool ELU>
__global__ __launch_bounds__(256) void attn_agg(const short* __restrict__ h,
                                                const float* __restrict__ es,
                                                const float* __restrict__ ed,
                                                const int* __restrict__ row_ptr,
                                                const int* __restrict__ srcs,
                                                const float* __restrict__ bias,
                                                short* __restrict__ out) {
    constexpr int HC = NHEAD * C;
    __shared__ float lw[DEG_CAP * NHEAD];
    __shared__ int   ssrc[DEG_CAP];
    __shared__ float red[256];
    __shared__ float sm_max[NHEAD];
    __shared__ float sm_den[NHEAD];

    int n = blockIdx.x;
    int start = row_ptr[n];
    int deg = row_ptr[n + 1] - start;
    int degc = deg < DEG_CAP ? deg : DEG_CAP;
    int t = threadIdx.x;
    float edv = ed[n * NHEAD + (t & 7)];

    for (int k = t; k < degc; k += 256) ssrc[k] = srcs[start + k];
    __syncthreads();

    // phase 1: e = leaky_relu(es[src]+ed[n]); stash in lw; per-head max
    float pm = -1e30f;
    for (int idx = t; idx < deg * NHEAD; idx += 256) {
        int k = idx >> 3, hh = idx & 7;
        int s = (k < degc) ? ssrc[k] : srcs[start + k];
        float e = es[s * NHEAD + hh] + edv;
        e = e > 0.f ? e : 0.2f * e;
        if (k < degc) lw[idx] = e;
        pm = fmaxf(pm, e);
    }
    red[t] = pm;
    __syncthreads();
    for (int off = 128; off >= 8; off >>= 1) {
        if (t < off) red[t] = fmaxf(red[t], red[t + off]);
        __syncthreads();
    }
    if (t < NHEAD) sm_max[t] = red[t];
    __syncthreads();

    // phase 2: w = exp(e - max) (from LDS), write back, per-head sum
    float mh = sm_max[t & 7];
    float ps = 0.f;
    for (int idx = t; idx < deg * NHEAD; idx += 256) {
        int k = idx >> 3, hh = idx & 7;
        float e;
        if (k < degc) e = lw[idx];
        else {
            int s = srcs[start + k];
            e = es[s * NHEAD + hh] + edv;
            e = e > 0.f ? e : 0.2f * e;
        }
        float wv = __expf(e - mh);
        if (k < degc) lw[idx] = wv;
        ps += wv;
    }
    red[t] = ps;
    __syncthreads();
    for (int off = 128; off >= 8; off >>= 1) {
        if (t < off) red[t] += red[t + off];
        __syncthreads();
    }
    if (t < NHEAD) sm_den[t] = red[t];
    __syncthreads();

    // normalize
    float invd = 1.0f / sm_den[t & 7];
    for (int idx = t; idx < degc * NHEAD; idx += 256) lw[idx] *= invd;
    __syncthreads();

    // phase 3: gather-weighted sum over sources
    for (int c = t; c < HC; c += 256) {
        int hh = c / C;
        float acc = 0.f;
        for (int k = 0; k < degc; k++)
            acc = fmaf(lw[k * NHEAD + hh], bf2f(h[(size_t)ssrc[k] * HC + c]), acc);
        if (deg > DEG_CAP) {   // robust fallback (not taken for this graph)
            float mhh = sm_max[hh];
            float dinvh = 1.0f / sm_den[hh];
            for (int k = DEG_CAP; k < deg; k++) {
                int s = srcs[start + k];
                float e = es[s * NHEAD + hh] + ed[n * NHEAD + hh];
                e = e > 0.f ? e : 0.2f * e;
                acc = fmaf(__expf(e - mhh) * dinvh, bf2f(h[(size_t)s * HC + c]), acc);
            }
        }
        float o = acc + bias[c];
        if (ELU) o = o > 0.f ? o : (__expf(o) - 1.0f);
        out[(size_t)n * HC + c] = f2bf(o);
    }
}

// ---------------------------------------------------------------------------
// Global mean pool (batch sorted), one block per graph, 512 features, bf16 in.
// ---------------------------------------------------------------------------
__global__ __launch_bounds__(256) void pool_kernel(const short* __restrict__ h,
                                                   const int* __restrict__ batch,
                                                   float* __restrict__ gout) {
    int g = blockIdx.x;
    int lo = 0, hi = NN;
    while (lo < hi) { int mid = (lo + hi) >> 1; if (batch[mid] < g) lo = mid + 1; else hi = mid; }
    int s = lo;
    lo = 0; hi = NN;
    while (lo < hi) { int mid = (lo + hi) >> 1; if (batch[mid] < g + 1) lo = mid + 1; else hi = mid; }
    int e = lo;
    int t = threadIdx.x;
    float a0 = 0.f, a1 = 0.f;
    for (int r = s; r < e; r++) {
        a0 += bf2f(h[(size_t)r * 512 + t]);
        a1 += bf2f(h[(size_t)r * 512 + 256 + t]);
    }
    float inv = 1.0f / fmaxf((float)(e - s), 1.0f);
    gout[g * 512 + t] = a0 * inv;
    gout[g * 512 + 256 + t] = a1 * inv;
}

// ---------------------------------------------------------------------------
// Final MLP: [64,512] -> elu(@lw1^T+lb1) -> @lw2^T+lb2 -> [64,2]
// ---------------------------------------------------------------------------
__global__ __launch_bounds__(64) void mlp_kernel(const float* __restrict__ g,
                                                 const float* __restrict__ lw1,
                                                 const float* __restrict__ lb1,
                                                 const float* __restrict__ lw2,
                                                 const float* __restrict__ lb2,
                                                 float* __restrict__ outp) {
    __shared__ float gv[512];
    __shared__ float y1[32];
    int b = blockIdx.x, t = threadIdx.x;
    for (int i = t; i < 512; i += 64) gv[i] = g[b * 512 + i];
    __syncthreads();
    if (t < 32) {
        float a = lb1[t];
        for (int k = 0; k < 512; k++) a = fmaf(gv[k], lw1[t * 512 + k], a);
        y1[t] = a > 0.f ? a : (__expf(a) - 1.0f);
    }
    __syncthreads();
    if (t < 2) {
        float a = lb2[t];
        for (int k = 0; k < 32; k++) a = fmaf(y1[k], lw2[t * 32 + k], a);
        outp[b * 2 + t] = a;
    }
}

// ---------------------------------------------------------------------------
// Launch
// ---------------------------------------------------------------------------
extern "C" void kernel_launch(void* const* d_in, const int* in_sizes, int n_in,
                              void* d_out, int out_size, void* d_ws, size_t ws_size,
                              hipStream_t stream) {
    (void)in_sizes; (void)n_in; (void)out_size; (void)ws_size;
    const float* x     = (const float*)d_in[0];
    const int*   ei    = (const int*)d_in[1];
    const int*   batch = (const int*)d_in[2];
    const float* W[4]  = {(const float*)d_in[3], (const float*)d_in[7],
                          (const float*)d_in[11], (const float*)d_in[15]};
    const float* As_[4] = {(const float*)d_in[4], (const float*)d_in[8],
                           (const float*)d_in[12], (const float*)d_in[16]};
    const float* Ad_[4] = {(const float*)d_in[5], (const float*)d_in[9],
                           (const float*)d_in[13], (const float*)d_in[17]};
    const float* Bi[4]  = {(const float*)d_in[6], (const float*)d_in[10],
                           (const float*)d_in[14], (const float*)d_in[18]};
    const float* lw1 = (const float*)d_in[19];
    const float* lb1 = (const float*)d_in[20];
    const float* lw2 = (const float*)d_in[21];
    const float* lb2 = (const float*)d_in[22];
    float* out = (float*)d_out;

    // workspace layout (bf16 buffers as short)
    short* Ab = (short*)d_ws;                      // [MPAD*512] activations
    short* Hb = Ab + (size_t)MPAD * 512;           // [MPAD*512] h = act @ W^T
    short* Wb = Hb + (size_t)MPAD * 512;           // bf16 weights, 294912 total
    short* Wb_[4] = {Wb, Wb + 65536, Wb + 196608, Wb + 229376};
    const int wsz[4] = {65536, 131072, 32768, 65536};
    float* esb  = (float*)(Wb + 294912);           // [NN*8]
    float* edb  = esb + NN * NHEAD;                // [NN*8]
    float* gbuf = edb + NN * NHEAD;                // [64*512]
    int* row_ptr = (int*)(gbuf + NGR * 512);       // [NN+1]
    int* cursor  = row_ptr + (NN + 1);             // [NN+1]
    int* srcs    = cursor + (NN + 1);              // [NEP]

    // ---- CSR build (shared by all 4 layers)
    hipMemsetAsync(cursor, 0, NN * sizeof(int), stream);
    count_deg<<<(NEP + 255) / 256, 256, 0, stream>>>(ei, cursor);
    scan_kernel<<<1, 1024, 0, stream>>>(cursor, row_ptr, NN);
    copy_int<<<(NN + 255) / 256, 256, 0, stream>>>(row_ptr, cursor, NN);
    scatter_edges<<<(NEP + 255) / 256, 256, 0, stream>>>(ei, cursor, srcs);

    // ---- bf16 conversions
    conv_x_pad<<<(MPAD * 128 + 255) / 256, 256, 0, stream>>>(x, Ab);
    for (int i = 0; i < 4; i++)
        conv_f2bf<<<(wsz[i] + 255) / 256, 256, 0, stream>>>(W[i], Wb_[i], wsz[i]);

    const int rowTiles = MPAD / 128;               // 391
    int eg = (NN * NHEAD + 255) / 256;

    // ---- layer 1: 128 -> 512 (C=64), ELU
    gemm_bf<<<rowTiles * 4, 256, 0, stream>>>(Ab, Wb_[0], Hb, 128, 512, 4);
    compute_esed<64><<<eg, 256, 0, stream>>>(Hb, As_[0], Ad_[0], esb, edb);
    attn_agg<64, true><<<NN, 256, 0, stream>>>(Hb, esb, edb, row_ptr, srcs, Bi[0], Ab);

    // ---- layer 2: 512 -> 256 (C=32), ELU
    gemm_bf<<<rowTiles * 2, 256, 0, stream>>>(Ab, Wb_[1], Hb, 512, 256, 2);
    compute_esed<32><<<eg, 256, 0, stream>>>(Hb, As_[1], Ad_[1], esb, edb);
    attn_agg<32, true><<<NN, 256, 0, stream>>>(Hb, esb, edb, row_ptr, srcs, Bi[1], Ab);

    // ---- layer 3: 256 -> 128 (C=16), ELU
    gemm_bf<<<rowTiles * 1, 256, 0, stream>>>(Ab, Wb_[2], Hb, 256, 128, 1);
    compute_esed<16><<<eg, 256, 0, stream>>>(Hb, As_[2], Ad_[2], esb, edb);
    attn_agg<16, true><<<NN, 256, 0, stream>>>(Hb, esb, edb, row_ptr, srcs, Bi[2], Ab);

    // ---- layer 4: 128 -> 512 (C=64), no ELU
    gemm_bf<<<rowTiles * 4, 256, 0, stream>>>(Ab, Wb_[3], Hb, 128, 512, 4);
    compute_esed<64><<<eg, 256, 0, stream>>>(Hb, As_[3], Ad_[3], esb, edb);
    attn_agg<64, false><<<NN, 256, 0, stream>>>(Hb, esb, edb, row_ptr, srcs, Bi[3], Ab);

    // ---- pool + MLP
    pool_kernel<<<NGR, 256, 0, stream>>>(Ab, batch, gbuf);
    mlp_kernel<<<NGR, 64, 0, stream>>>(gbuf, lw1, lb1, lw2, lb2, out);
}

// Round 3
// 1102.685 us; speedup vs baseline: 1.6925x; 1.2341x over previous
//
#include <hip/hip_runtime.h>
#include <math.h>

// ---------------------------------------------------------------------------
// Problem constants
// ---------------------------------------------------------------------------
#define NN 50000          // nodes
#define NE 800000         // edges (before self loops)
#define NEP (NE + NN)     // edges incl self loops
#define NGR 64            // graphs
#define NHEAD 8
#define MPAD 50048        // 391 * 128

typedef short short8 __attribute__((ext_vector_type(8)));
typedef float floatx4 __attribute__((ext_vector_type(4)));

__device__ inline float bf2f(short s) {
    union { unsigned u; float f; } v;
    v.u = ((unsigned)(unsigned short)s) << 16;
    return v.f;
}
__device__ inline float bf2f_lo(unsigned p) {      // low bf16 of packed pair
    union { unsigned u; float f; } v; v.u = p << 16; return v.f;
}
__device__ inline float bf2f_hi(unsigned p) {      // high bf16 of packed pair
    union { unsigned u; float f; } v; v.u = p & 0xffff0000u; return v.f;
}
__device__ inline short f2bf(float f) {
    union { float f; unsigned u; } v; v.f = f;
    unsigned r = v.u + 0x7fffu + ((v.u >> 16) & 1u);   // RNE
    return (short)(r >> 16);
}

// ---------------------------------------------------------------------------
// CSR build (dst-major). Edge e<NE: src=ei[e], dst=ei[NE+e]; else self loop.
// ---------------------------------------------------------------------------
__global__ void count_deg(const int* __restrict__ ei, int* __restrict__ deg) {
    int e = blockIdx.x * 256 + threadIdx.x;
    if (e >= NEP) return;
    int d = (e < NE) ? ei[NE + e] : (e - NE);
    atomicAdd(&deg[d], 1);
}

__global__ void scan_kernel(const int* __restrict__ deg, int* __restrict__ row_ptr, int n) {
    __shared__ int sd[1024];
    __shared__ int soff;
    int t = threadIdx.x;
    if (t == 0) soff = 0;
    __syncthreads();
    for (int base = 0; base < n; base += 1024) {
        int i = base + t;
        int v = (i < n) ? deg[i] : 0;
        sd[t] = v;
        __syncthreads();
        for (int off = 1; off < 1024; off <<= 1) {
            int tmp = (t >= off) ? sd[t - off] : 0;
            __syncthreads();
            sd[t] += tmp;
            __syncthreads();
        }
        int off0 = soff;
        if (i < n) row_ptr[i] = off0 + sd[t] - v;   // exclusive
        __syncthreads();
        if (t == 1023) soff = off0 + sd[1023];
        __syncthreads();
    }
    if (t == 0) row_ptr[n] = soff;
}

__global__ void copy_int(const int* __restrict__ a, int* __restrict__ b, int n) {
    int i = blockIdx.x * 256 + threadIdx.x;
    if (i < n) b[i] = a[i];
}

__global__ void scatter_edges(const int* __restrict__ ei, int* __restrict__ cursor,
                              int* __restrict__ srcs) {
    int e = blockIdx.x * 256 + threadIdx.x;
    if (e >= NEP) return;
    int s, d;
    if (e < NE) { s = ei[e]; d = ei[NE + e]; }
    else        { s = e - NE; d = e - NE; }
    int pos = atomicAdd(&cursor[d], 1);
    srcs[pos] = s;
}

// ---------------------------------------------------------------------------
// fp32 -> bf16 conversions
// ---------------------------------------------------------------------------
__global__ void conv_f2bf(const float* __restrict__ in, short* __restrict__ out, int n) {
    int i = blockIdx.x * 256 + threadIdx.x;
    if (i < n) out[i] = f2bf(in[i]);
}

__global__ void conv_x_pad(const float* __restrict__ x, short* __restrict__ xb) {
    int i = blockIdx.x * 256 + threadIdx.x;
    if (i >= MPAD * 128) return;
    int r = i >> 7;
    xb[i] = (r < NN) ? f2bf(x[i]) : (short)0;
}

// ---------------------------------------------------------------------------
// bf16 MFMA GEMM: C[MPAD,Nc](bf16) = A[MPAD,K](bf16) @ B[Nc,K](bf16)^T
// 128x128 tile, BK=32, 4 waves, each wave 64x64 via 4x4 mfma_16x16x32_bf16.
// ---------------------------------------------------------------------------
#define LDA 40   // padded LDS row stride in shorts (80 B = 20 banks: 2-way max)
__global__ __launch_bounds__(256) void gemm_bf(const short* __restrict__ A,
                                               const short* __restrict__ B,
                                               short* __restrict__ C,
                                               int K, int Nc, int colTiles) {
    __shared__ __align__(16) short As[128 * LDA];
    __shared__ __align__(16) short Bs[128 * LDA];
    int bx = blockIdx.x % colTiles;
    int by = blockIdx.x / colTiles;
    int row0 = by * 128, col0 = bx * 128;
    int t = threadIdx.x;
    int lane = t & 63, w = t >> 6;
    int wr = (w >> 1) * 64, wc = (w & 1) * 64;
    int lrow = lane & 15, lq = lane >> 4;

    floatx4 acc[4][4];
#pragma unroll
    for (int i = 0; i < 4; i++)
#pragma unroll
        for (int j = 0; j < 4; j++) acc[i][j] = (floatx4)0.0f;

    for (int k0 = 0; k0 < K; k0 += 32) {
#pragma unroll
        for (int i = 0; i < 2; i++) {
            int chunk = t + i * 256;          // 0..511
            int r = chunk >> 2;
            int kc = (chunk & 3) * 8;
            *(short8*)&As[r * LDA + kc] = *(const short8*)&A[(size_t)(row0 + r) * K + k0 + kc];
            *(short8*)&Bs[r * LDA + kc] = *(const short8*)&B[(size_t)(col0 + r) * K + k0 + kc];
        }
        __syncthreads();
        short8 af[4], bfr[4];
#pragma unroll
        for (int i = 0; i < 4; i++)
            af[i] = *(const short8*)&As[(wr + i * 16 + lrow) * LDA + lq * 8];
#pragma unroll
        for (int j = 0; j < 4; j++)
            bfr[j] = *(const short8*)&Bs[(wc + j * 16 + lrow) * LDA + lq * 8];
#pragma unroll
        for (int i = 0; i < 4; i++)
#pragma unroll
            for (int j = 0; j < 4; j++)
                acc[i][j] = __builtin_amdgcn_mfma_f32_16x16x32_bf16(af[i], bfr[j], acc[i][j], 0, 0, 0);
        __syncthreads();
    }
#pragma unroll
    for (int i = 0; i < 4; i++)
#pragma unroll
        for (int j = 0; j < 4; j++)
#pragma unroll
            for (int r = 0; r < 4; r++) {
                int row = row0 + wr + i * 16 + lq * 4 + r;
                int col = col0 + wc + j * 16 + lrow;
                C[(size_t)row * Nc + col] = f2bf(acc[i][j][r]);
            }
}

// ---------------------------------------------------------------------------
// es/ed: per (node, head) dot over C channels (h bf16, a fp32).
// ---------------------------------------------------------------------------
template <int C>
__global__ void compute_esed(const short* __restrict__ h, const float* __restrict__ a_s,
                             const float* __restrict__ a_d, float* __restrict__ es,
                             float* __restrict__ ed) {
    int gid = blockIdx.x * 256 + threadIdx.x;
    if (gid >= NN * NHEAD) return;
    int n = gid >> 3, hh = gid & 7;
    const short* hr = h + (size_t)n * NHEAD * C + hh * C;
    const float* as = a_s + hh * C;
    const float* ad = a_d + hh * C;
    float s1 = 0.f, s2 = 0.f;
#pragma unroll
    for (int c = 0; c < C; c += 8) {
        short8 hv = *(const short8*)&hr[c];
#pragma unroll
        for (int j = 0; j < 8; j++) {
            float hvf = bf2f(hv[j]);
            s1 = fmaf(hvf, as[c + j], s1);
            s2 = fmaf(hvf, ad[c + j], s2);
        }
    }
    es[gid] = s1;
    ed[gid] = s2;
}

// ---------------------------------------------------------------------------
// Attention softmax + aggregation, one block per dst node, CSR, no atomics.
// h bf16 in, out bf16, fp32 accumulation. HC=512 path vectorized 2x.
// ---------------------------------------------------------------------------
#define DEG_CAP 256
template <int C, bool ELU>
__global__ __launch_bounds__(256) void attn_agg(const short* __restrict__ h,
                                                const float* __restrict__ es,
                                                const float* __restrict__ ed,
                                                const int* __restrict__ row_ptr,
                                                const int* __restrict__ srcs,
                                                const float* __restrict__ bias,
                                                short* __restrict__ out) {
    constexpr int HC = NHEAD * C;
    __shared__ float lw[DEG_CAP * NHEAD];
    __shared__ int   ssrc[DEG_CAP];
    __shared__ float red[256];
    __shared__ float sm_max[NHEAD];
    __shared__ float sm_den[NHEAD];

    int n = blockIdx.x;
    int start = row_ptr[n];
    int deg = row_ptr[n + 1] - start;
    int degc = deg < DEG_CAP ? deg : DEG_CAP;
    int t = threadIdx.x;
    float edv = ed[n * NHEAD + (t & 7)];

    for (int k = t; k < degc; k += 256) ssrc[k] = srcs[start + k];
    __syncthreads();

    // phase 1: e = leaky_relu(es[src]+ed[n]); stash in lw; per-head max
    float pm = -1e30f;
    for (int idx = t; idx < deg * NHEAD; idx += 256) {
        int k = idx >> 3, hh = idx & 7;
        int s = (k < degc) ? ssrc[k] : srcs[start + k];
        float e = es[s * NHEAD + hh] + edv;
        e = e > 0.f ? e : 0.2f * e;
        if (k < degc) lw[idx] = e;
        pm = fmaxf(pm, e);
    }
    red[t] = pm;
    __syncthreads();
    for (int off = 128; off >= 8; off >>= 1) {
        if (t < off) red[t] = fmaxf(red[t], red[t + off]);
        __syncthreads();
    }
    if (t < NHEAD) sm_max[t] = red[t];
    __syncthreads();

    // phase 2: w = exp(e - max) (from LDS), write back, per-head sum
    float mh = sm_max[t & 7];
    float ps = 0.f;
    for (int idx = t; idx < deg * NHEAD; idx += 256) {
        int k = idx >> 3, hh = idx & 7;
        float e;
        if (k < degc) e = lw[idx];
        else {
            int s = srcs[start + k];
            e = es[s * NHEAD + hh] + edv;
            e = e > 0.f ? e : 0.2f * e;
        }
        float wv = __expf(e - mh);
        if (k < degc) lw[idx] = wv;
        ps += wv;
    }
    red[t] = ps;
    __syncthreads();
    for (int off = 128; off >= 8; off >>= 1) {
        if (t < off) red[t] += red[t + off];
        __syncthreads();
    }
    if (t < NHEAD) sm_den[t] = red[t];
    __syncthreads();

    // normalize
    float invd = 1.0f / sm_den[t & 7];
    for (int idx = t; idx < degc * NHEAD; idx += 256) lw[idx] *= invd;
    __syncthreads();

    // phase 3: gather-weighted sum over sources
    if constexpr (HC == 512) {
        // vectorized: each thread owns 2 adjacent channels (one dword)
        int c0 = t * 2;
        int hh = c0 / C;
        float acc0 = 0.f, acc1 = 0.f;
        for (int k = 0; k < degc; k++) {
            unsigned hv = *(const unsigned*)&h[(size_t)ssrc[k] * 512 + c0];
            float wv = lw[k * NHEAD + hh];
            acc0 = fmaf(wv, bf2f_lo(hv), acc0);
            acc1 = fmaf(wv, bf2f_hi(hv), acc1);
        }
        if (deg > DEG_CAP) {
            float mhh = sm_max[hh];
            float dinvh = 1.0f / sm_den[hh];
            for (int k = DEG_CAP; k < deg; k++) {
                int s = srcs[start + k];
                float e = es[s * NHEAD + hh] + ed[n * NHEAD + hh];
                e = e > 0.f ? e : 0.2f * e;
                float wv = __expf(e - mhh) * dinvh;
                unsigned hv = *(const unsigned*)&h[(size_t)s * 512 + c0];
                acc0 = fmaf(wv, bf2f_lo(hv), acc0);
                acc1 = fmaf(wv, bf2f_hi(hv), acc1);
            }
        }
        float o0 = acc0 + bias[c0];
        float o1 = acc1 + bias[c0 + 1];
        if (ELU) {
            o0 = o0 > 0.f ? o0 : (__expf(o0) - 1.0f);
            o1 = o1 > 0.f ? o1 : (__expf(o1) - 1.0f);
        }
        unsigned pk = ((unsigned)(unsigned short)f2bf(o0)) |
                      (((unsigned)(unsigned short)f2bf(o1)) << 16);
        *(unsigned*)&out[(size_t)n * 512 + c0] = pk;
    } else {
        for (int c = t; c < HC; c += 256) {
            int hh = c / C;
            float acc = 0.f;
            for (int k = 0; k < degc; k++)
                acc = fmaf(lw[k * NHEAD + hh], bf2f(h[(size_t)ssrc[k] * HC + c]), acc);
            if (deg > DEG_CAP) {
                float mhh = sm_max[hh];
                float dinvh = 1.0f / sm_den[hh];
                for (int k = DEG_CAP; k < deg; k++) {
                    int s = srcs[start + k];
                    float e = es[s * NHEAD + hh] + ed[n * NHEAD + hh];
                    e = e > 0.f ? e : 0.2f * e;
                    acc = fmaf(__expf(e - mhh) * dinvh, bf2f(h[(size_t)s * HC + c]), acc);
                }
            }
            float o = acc + bias[c];
            if (ELU) o = o > 0.f ? o : (__expf(o) - 1.0f);
            out[(size_t)n * HC + c] = f2bf(o);
        }
    }
}

// ---------------------------------------------------------------------------
// Global mean pool: 64 graphs x 8 feature-chunks of 64; 4 row stripes/block.
// ---------------------------------------------------------------------------
__global__ __launch_bounds__(256) void pool_kernel(const short* __restrict__ h,
                                                   const int* __restrict__ batch,
                                                   float* __restrict__ gout) {
    __shared__ float red[256];
    int g = blockIdx.x >> 3;
    int fc = (blockIdx.x & 7) * 64;
    int lo = 0, hi = NN;
    while (lo < hi) { int mid = (lo + hi) >> 1; if (batch[mid] < g) lo = mid + 1; else hi = mid; }
    int s = lo;
    lo = 0; hi = NN;
    while (lo < hi) { int mid = (lo + hi) >> 1; if (batch[mid] < g + 1) lo = mid + 1; else hi = mid; }
    int e = lo;
    int t = threadIdx.x;
    int f = t & 63, stripe = t >> 6;
    float a = 0.f;
    for (int r = s + stripe; r < e; r += 4)
        a += bf2f(h[(size_t)r * 512 + fc + f]);
    red[t] = a;
    __syncthreads();
    if (t < 128) red[t] += red[t + 128];
    __syncthreads();
    if (t < 64) {
        float inv = 1.0f / fmaxf((float)(e - s), 1.0f);
        gout[g * 512 + fc + t] = (red[t] + red[t + 64]) * inv;
    }
}

// ---------------------------------------------------------------------------
// Final MLP: [64,512] -> elu(@lw1^T+lb1) -> @lw2^T+lb2 -> [64,2]
// ---------------------------------------------------------------------------
__global__ __launch_bounds__(64) void mlp_kernel(const float* __restrict__ g,
                                                 const float* __restrict__ lw1,
                                                 const float* __restrict__ lb1,
                                                 const float* __restrict__ lw2,
                                                 const float* __restrict__ lb2,
                                                 float* __restrict__ outp) {
    __shared__ float gv[512];
    __shared__ float y1[32];
    int b = blockIdx.x, t = threadIdx.x;
    for (int i = t; i < 512; i += 64) gv[i] = g[b * 512 + i];
    __syncthreads();
    if (t < 32) {
        float a = lb1[t];
        for (int k = 0; k < 512; k++) a = fmaf(gv[k], lw1[t * 512 + k], a);
        y1[t] = a > 0.f ? a : (__expf(a) - 1.0f);
    }
    __syncthreads();
    if (t < 2) {
        float a = lb2[t];
        for (int k = 0; k < 32; k++) a = fmaf(y1[k], lw2[t * 32 + k], a);
        outp[b * 2 + t] = a;
    }
}

// ---------------------------------------------------------------------------
// Launch
// ---------------------------------------------------------------------------
extern "C" void kernel_launch(void* const* d_in, const int* in_sizes, int n_in,
                              void* d_out, int out_size, void* d_ws, size_t ws_size,
                              hipStream_t stream) {
    (void)in_sizes; (void)n_in; (void)out_size; (void)ws_size;
    const float* x     = (const float*)d_in[0];
    const int*   ei    = (const int*)d_in[1];
    const int*   batch = (const int*)d_in[2];
    const float* W[4]  = {(const float*)d_in[3], (const float*)d_in[7],
                          (const float*)d_in[11], (const float*)d_in[15]};
    const float* As_[4] = {(const float*)d_in[4], (const float*)d_in[8],
                           (const float*)d_in[12], (const float*)d_in[16]};
    const float* Ad_[4] = {(const float*)d_in[5], (const float*)d_in[9],
                           (const float*)d_in[13], (const float*)d_in[17]};
    const float* Bi[4]  = {(const float*)d_in[6], (const float*)d_in[10],
                           (const float*)d_in[14], (const float*)d_in[18]};
    const float* lw1 = (const float*)d_in[19];
    const float* lb1 = (const float*)d_in[20];
    const float* lw2 = (const float*)d_in[21];
    const float* lb2 = (const float*)d_in[22];
    float* out = (float*)d_out;

    // workspace layout (bf16 buffers as short)
    short* Ab = (short*)d_ws;                      // [MPAD*512] activations
    short* Hb = Ab + (size_t)MPAD * 512;           // [MPAD*512] h = act @ W^T
    short* Wb = Hb + (size_t)MPAD * 512;           // bf16 weights
    short* Wb_[4] = {Wb, Wb + 65536, Wb + 196608, Wb + 229376};
    const int wsz[4] = {65536, 131072, 32768, 65536};
    float* esb  = (float*)(Wb + 294912);           // [NN*8]
    float* edb  = esb + NN * NHEAD;                // [NN*8]
    float* gbuf = edb + NN * NHEAD;                // [64*512]
    int* row_ptr = (int*)(gbuf + NGR * 512);       // [NN+1]
    int* cursor  = row_ptr + (NN + 1);             // [NN+1]
    int* srcs    = cursor + (NN + 1);              // [NEP]

    // ---- CSR build (shared by all 4 layers)
    hipMemsetAsync(cursor, 0, NN * sizeof(int), stream);
    count_deg<<<(NEP + 255) / 256, 256, 0, stream>>>(ei, cursor);
    scan_kernel<<<1, 1024, 0, stream>>>(cursor, row_ptr, NN);
    copy_int<<<(NN + 255) / 256, 256, 0, stream>>>(row_ptr, cursor, NN);
    scatter_edges<<<(NEP + 255) / 256, 256, 0, stream>>>(ei, cursor, srcs);

    // ---- bf16 conversions
    conv_x_pad<<<(MPAD * 128 + 255) / 256, 256, 0, stream>>>(x, Ab);
    for (int i = 0; i < 4; i++)
        conv_f2bf<<<(wsz[i] + 255) / 256, 256, 0, stream>>>(W[i], Wb_[i], wsz[i]);

    const int rowTiles = MPAD / 128;               // 391
    int eg = (NN * NHEAD + 255) / 256;

    // ---- layer 1: 128 -> 512 (C=64), ELU
    gemm_bf<<<rowTiles * 4, 256, 0, stream>>>(Ab, Wb_[0], Hb, 128, 512, 4);
    compute_esed<64><<<eg, 256, 0, stream>>>(Hb, As_[0], Ad_[0], esb, edb);
    attn_agg<64, true><<<NN, 256, 0, stream>>>(Hb, esb, edb, row_ptr, srcs, Bi[0], Ab);

    // ---- layer 2: 512 -> 256 (C=32), ELU
    gemm_bf<<<rowTiles * 2, 256, 0, stream>>>(Ab, Wb_[1], Hb, 512, 256, 2);
    compute_esed<32><<<eg, 256, 0, stream>>>(Hb, As_[1], Ad_[1], esb, edb);
    attn_agg<32, true><<<NN, 256, 0, stream>>>(Hb, esb, edb, row_ptr, srcs, Bi[1], Ab);

    // ---- layer 3: 256 -> 128 (C=16), ELU
    gemm_bf<<<rowTiles * 1, 256, 0, stream>>>(Ab, Wb_[2], Hb, 256, 128, 1);
    compute_esed<16><<<eg, 256, 0, stream>>>(Hb, As_[2], Ad_[2], esb, edb);
    attn_agg<16, true><<<NN, 256, 0, stream>>>(Hb, esb, edb, row_ptr, srcs, Bi[2], Ab);

    // ---- layer 4: 128 -> 512 (C=64), no ELU
    gemm_bf<<<rowTiles * 4, 256, 0, stream>>>(Ab, Wb_[3], Hb, 128, 512, 4);
    compute_esed<64><<<eg, 256, 0, stream>>>(Hb, As_[3], Ad_[3], esb, edb);
    attn_agg<64, false><<<NN, 256, 0, stream>>>(Hb, esb, edb, row_ptr, srcs, Bi[3], Ab);

    // ---- pool + MLP
    pool_kernel<<<NGR * 8, 256, 0, stream>>>(Ab, batch, gbuf);
    mlp_kernel<<<NGR, 64, 0, stream>>>(gbuf, lw1, lb1, lw2, lb2, out);
}

// Round 4
// 1001.278 us; speedup vs baseline: 1.8640x; 1.1013x over previous
//
#include <hip/hip_runtime.h>
#include <math.h>

// ---------------------------------------------------------------------------
// Problem constants
// ---------------------------------------------------------------------------
#define NN 50000          // nodes
#define NE 800000         // edges (before self loops)
#define NEP (NE + NN)     // edges incl self loops
#define NGR 64            // graphs
#define NHEAD 8
#define MPAD 50048        // 391 * 128

typedef short short8 __attribute__((ext_vector_type(8)));
typedef float floatx4 __attribute__((ext_vector_type(4)));
typedef unsigned uintx4 __attribute__((ext_vector_type(4)));

__device__ inline float bf2f(short s) {
    union { unsigned u; float f; } v;
    v.u = ((unsigned)(unsigned short)s) << 16;
    return v.f;
}
__device__ inline float bf2f_lo(unsigned p) {
    union { unsigned u; float f; } v; v.u = p << 16; return v.f;
}
__device__ inline float bf2f_hi(unsigned p) {
    union { unsigned u; float f; } v; v.u = p & 0xffff0000u; return v.f;
}
__device__ inline short f2bf(float f) {
    union { float f; unsigned u; } v; v.f = f;
    unsigned r = v.u + 0x7fffu + ((v.u >> 16) & 1u);   // RNE
    return (short)(r >> 16);
}

// ---------------------------------------------------------------------------
// CSR build (dst-major). Edge e<NE: src=ei[e], dst=ei[NE+e]; else self loop.
// ---------------------------------------------------------------------------
__global__ void count_deg(const int* __restrict__ ei, int* __restrict__ deg) {
    int e = blockIdx.x * 256 + threadIdx.x;
    if (e >= NEP) return;
    int d = (e < NE) ? ei[NE + e] : (e - NE);
    atomicAdd(&deg[d], 1);
}

// hierarchical scan: local 1024-wide scans -> serial scan of 49 block sums -> add
__global__ __launch_bounds__(1024) void scan_local(const int* __restrict__ deg,
                                                   int* __restrict__ out,
                                                   int* __restrict__ bsum, int n) {
    __shared__ int sd[1024];
    int b = blockIdx.x, t = threadIdx.x;
    int i = b * 1024 + t;
    int v = (i < n) ? deg[i] : 0;
    sd[t] = v;
    __syncthreads();
    for (int off = 1; off < 1024; off <<= 1) {
        int tmp = (t >= off) ? sd[t - off] : 0;
        __syncthreads();
        sd[t] += tmp;
        __syncthreads();
    }
    if (i < n) out[i] = sd[t] - v;          // exclusive
    if (t == 1023) bsum[b] = sd[1023];
}

__global__ void scan_bsum(int* __restrict__ bsum, int nb) {
    if (threadIdx.x == 0) {
        int s = 0;
        for (int i = 0; i < nb; i++) { int v = bsum[i]; bsum[i] = s; s += v; }
        bsum[nb] = s;
    }
}

__global__ void scan_add(int* __restrict__ row_ptr, int* __restrict__ cursor,
                         const int* __restrict__ bsum, int n, int nb) {
    int i = blockIdx.x * 256 + threadIdx.x;
    if (i < n) {
        int v = row_ptr[i] + bsum[i >> 10];
        row_ptr[i] = v;
        cursor[i] = v;
    } else if (i == n) {
        row_ptr[n] = bsum[nb];
    }
}

__global__ void scatter_edges(const int* __restrict__ ei, int* __restrict__ cursor,
                              int* __restrict__ srcs) {
    int e = blockIdx.x * 256 + threadIdx.x;
    if (e >= NEP) return;
    int s, d;
    if (e < NE) { s = ei[e]; d = ei[NE + e]; }
    else        { s = e - NE; d = e - NE; }
    int pos = atomicAdd(&cursor[d], 1);
    srcs[pos] = s;
}

// ---------------------------------------------------------------------------
// fp32 -> bf16 conversions
// ---------------------------------------------------------------------------
__global__ void conv_f2bf(const float* __restrict__ in, short* __restrict__ out, int n) {
    int i = blockIdx.x * 256 + threadIdx.x;
    if (i < n) out[i] = f2bf(in[i]);
}

__global__ void conv_x_pad4(const float* __restrict__ x, short* __restrict__ xb) {
    int i = blockIdx.x * 256 + threadIdx.x;          // one float4 per thread
    if (i >= MPAD * 32) return;
    int r = i >> 5;
    short4 o;
    if (r < NN) {
        float4 v = *(const float4*)&x[(size_t)i * 4];
        o.x = f2bf(v.x); o.y = f2bf(v.y); o.z = f2bf(v.z); o.w = f2bf(v.w);
    } else {
        o.x = o.y = o.z = o.w = 0;
    }
    *(short4*)&xb[(size_t)i * 4] = o;
}

// ---------------------------------------------------------------------------
// bf16 MFMA GEMM: C[MPAD,Nc](bf16) = A[MPAD,K](bf16) @ B[Nc,K](bf16)^T
// 128x128 tile, BK=32, 4 waves, each wave 64x64 via 4x4 mfma_16x16x32_bf16.
// ---------------------------------------------------------------------------
#define LDA 40   // padded LDS row stride in shorts (80 B = 20 banks: 2-way max)
__global__ __launch_bounds__(256) void gemm_bf(const short* __restrict__ A,
                                               const short* __restrict__ B,
                                               short* __restrict__ C,
                                               int K, int Nc, int colTiles) {
    __shared__ __align__(16) short As[128 * LDA];
    __shared__ __align__(16) short Bs[128 * LDA];
    int bx = blockIdx.x % colTiles;
    int by = blockIdx.x / colTiles;
    int row0 = by * 128, col0 = bx * 128;
    int t = threadIdx.x;
    int lane = t & 63, w = t >> 6;
    int wr = (w >> 1) * 64, wc = (w & 1) * 64;
    int lrow = lane & 15, lq = lane >> 4;

    floatx4 acc[4][4];
#pragma unroll
    for (int i = 0; i < 4; i++)
#pragma unroll
        for (int j = 0; j < 4; j++) acc[i][j] = (floatx4)0.0f;

    for (int k0 = 0; k0 < K; k0 += 32) {
#pragma unroll
        for (int i = 0; i < 2; i++) {
            int chunk = t + i * 256;
            int r = chunk >> 2;
            int kc = (chunk & 3) * 8;
            *(short8*)&As[r * LDA + kc] = *(const short8*)&A[(size_t)(row0 + r) * K + k0 + kc];
            *(short8*)&Bs[r * LDA + kc] = *(const short8*)&B[(size_t)(col0 + r) * K + k0 + kc];
        }
        __syncthreads();
        short8 af[4], bfr[4];
#pragma unroll
        for (int i = 0; i < 4; i++)
            af[i] = *(const short8*)&As[(wr + i * 16 + lrow) * LDA + lq * 8];
#pragma unroll
        for (int j = 0; j < 4; j++)
            bfr[j] = *(const short8*)&Bs[(wc + j * 16 + lrow) * LDA + lq * 8];
#pragma unroll
        for (int i = 0; i < 4; i++)
#pragma unroll
            for (int j = 0; j < 4; j++)
                acc[i][j] = __builtin_amdgcn_mfma_f32_16x16x32_bf16(af[i], bfr[j], acc[i][j], 0, 0, 0);
        __syncthreads();
    }
#pragma unroll
    for (int i = 0; i < 4; i++)
#pragma unroll
        for (int j = 0; j < 4; j++)
#pragma unroll
            for (int r = 0; r < 4; r++) {
                int row = row0 + wr + i * 16 + lq * 4 + r;
                int col = col0 + wc + j * 16 + lrow;
                C[(size_t)row * Nc + col] = f2bf(acc[i][j][r]);
            }
}

// ---------------------------------------------------------------------------
// es/ed: per (node, head) dot over C channels (h bf16, a fp32).
// ---------------------------------------------------------------------------
template <int C>
__global__ void compute_esed(const short* __restrict__ h, const float* __restrict__ a_s,
                             const float* __restrict__ a_d, float* __restrict__ es,
                             float* __restrict__ ed) {
    int gid = blockIdx.x * 256 + threadIdx.x;
    if (gid >= NN * NHEAD) return;
    int n = gid >> 3, hh = gid & 7;
    const short* hr = h + (size_t)n * NHEAD * C + hh * C;
    const float* as = a_s + hh * C;
    const float* ad = a_d + hh * C;
    float s1 = 0.f, s2 = 0.f;
#pragma unroll
    for (int c = 0; c < C; c += 8) {
        short8 hv = *(const short8*)&hr[c];
#pragma unroll
        for (int j = 0; j < 8; j++) {
            float hvf = bf2f(hv[j]);
            s1 = fmaf(hvf, as[c + j], s1);
            s2 = fmaf(hvf, ad[c + j], s2);
        }
    }
    es[gid] = s1;
    ed[gid] = s2;
}

// ---------------------------------------------------------------------------
// Attention softmax + aggregation, one block per dst node, CSR, no atomics.
// Phase 3: each thread owns 8 channels (16B load/lane), NG edge-groups,
// cross-group LDS reduction. sm_den holds reciprocal; normalize fused.
// ---------------------------------------------------------------------------
#define DEG_CAP 256
template <int C, bool ELU>
__global__ __launch_bounds__(256) void attn_agg(const short* __restrict__ h,
                                                const float* __restrict__ es,
                                                const float* __restrict__ ed,
                                                const int* __restrict__ row_ptr,
                                                const int* __restrict__ srcs,
                                                const float* __restrict__ bias,
                                                short* __restrict__ out) {
    constexpr int HC = NHEAD * C;
    constexpr int TPR = HC / 8;        // threads covering one row, 8 ch each
    constexpr int NG = 256 / TPR;      // edge groups
    __shared__ float lw[DEG_CAP * NHEAD];
    __shared__ int   ssrc[DEG_CAP];
    __shared__ float red[256];
    __shared__ float redv[256 * 8];
    __shared__ float sm_max[NHEAD];
    __shared__ float sm_den[NHEAD];    // holds 1/denominator

    int n = blockIdx.x;
    int start = row_ptr[n];
    int deg = row_ptr[n + 1] - start;
    int degc = deg < DEG_CAP ? deg : DEG_CAP;
    int t = threadIdx.x;
    float edv = ed[n * NHEAD + (t & 7)];

    for (int k = t; k < degc; k += 256) ssrc[k] = srcs[start + k];
    __syncthreads();

    // phase 1: e = leaky_relu(es[src]+ed[n]); stash; per-head max
    float pm = -1e30f;
    for (int idx = t; idx < deg * NHEAD; idx += 256) {
        int k = idx >> 3, hh = idx & 7;
        int s = (k < degc) ? ssrc[k] : srcs[start + k];
        float e = es[s * NHEAD + hh] + edv;
        e = e > 0.f ? e : 0.2f * e;
        if (k < degc) lw[idx] = e;
        pm = fmaxf(pm, e);
    }
    red[t] = pm;
    __syncthreads();
    for (int off = 128; off >= 8; off >>= 1) {
        if (t < off) red[t] = fmaxf(red[t], red[t + off]);
        __syncthreads();
    }
    if (t < NHEAD) sm_max[t] = red[t];
    __syncthreads();

    // phase 2: w = exp(e - max), write back, per-head sum
    float mh = sm_max[t & 7];
    float ps = 0.f;
    for (int idx = t; idx < deg * NHEAD; idx += 256) {
        int k = idx >> 3, hh = idx & 7;
        float e;
        if (k < degc) e = lw[idx];
        else {
            int s = srcs[start + k];
            e = es[s * NHEAD + hh] + edv;
            e = e > 0.f ? e : 0.2f * e;
        }
        float wv = __expf(e - mh);
        if (k < degc) lw[idx] = wv;
        ps += wv;
    }
    red[t] = ps;
    __syncthreads();
    for (int off = 128; off >= 8; off >>= 1) {
        if (t < off) red[t] += red[t + off];
        __syncthreads();
    }
    if (t < NHEAD) sm_den[t] = 1.0f / red[t];
    __syncthreads();

    // phase 3: gather 16B/lane, edges split over NG groups
    int r = t & (TPR - 1);
    int g = t / TPR;
    int c0 = r * 8;
    int hh = c0 / C;
    float invd = sm_den[hh];
    float acc[8];
#pragma unroll
    for (int j = 0; j < 8; j++) acc[j] = 0.f;

    for (int k = g; k < deg; k += NG) {
        int s; float wv;
        if (k < degc) {
            s = ssrc[k];
            wv = lw[k * NHEAD + hh] * invd;
        } else {               // robust fallback (not taken for this graph)
            s = srcs[start + k];
            float e = es[s * NHEAD + hh] + ed[n * NHEAD + hh];
            e = e > 0.f ? e : 0.2f * e;
            wv = __expf(e - sm_max[hh]) * invd;
        }
        uintx4 hv = *(const uintx4*)&h[(size_t)s * HC + c0];
#pragma unroll
        for (int j = 0; j < 4; j++) {
            acc[2 * j]     = fmaf(wv, bf2f_lo(hv[j]), acc[2 * j]);
            acc[2 * j + 1] = fmaf(wv, bf2f_hi(hv[j]), acc[2 * j + 1]);
        }
    }
    *(floatx4*)&redv[t * 8]     = *(floatx4*)&acc[0];
    *(floatx4*)&redv[t * 8 + 4] = *(floatx4*)&acc[4];
    __syncthreads();
    if (g == 0) {
#pragma unroll
        for (int gg = 1; gg < NG; gg++) {
            const float* p = &redv[(gg * TPR + r) * 8];
#pragma unroll
            for (int j = 0; j < 8; j++) acc[j] += p[j];
        }
        unsigned pk[4];
#pragma unroll
        for (int j = 0; j < 4; j++) {
            float o0 = acc[2 * j] + bias[c0 + 2 * j];
            float o1 = acc[2 * j + 1] + bias[c0 + 2 * j + 1];
            if (ELU) {
                o0 = o0 > 0.f ? o0 : (__expf(o0) - 1.0f);
                o1 = o1 > 0.f ? o1 : (__expf(o1) - 1.0f);
            }
            pk[j] = ((unsigned)(unsigned short)f2bf(o0)) |
                    (((unsigned)(unsigned short)f2bf(o1)) << 16);
        }
        *(uintx4*)&out[(size_t)n * HC + c0] = *(uintx4*)pk;
    }
}

// ---------------------------------------------------------------------------
// Global mean pool: 64 graphs x 8 feature-chunks of 64; 4 row stripes/block.
// ---------------------------------------------------------------------------
__global__ __launch_bounds__(256) void pool_kernel(const short* __restrict__ h,
                                                   const int* __restrict__ batch,
                                                   float* __restrict__ gout) {
    __shared__ float red[256];
    int g = blockIdx.x >> 3;
    int fc = (blockIdx.x & 7) * 64;
    int lo = 0, hi = NN;
    while (lo < hi) { int mid = (lo + hi) >> 1; if (batch[mid] < g) lo = mid + 1; else hi = mid; }
    int s = lo;
    lo = 0; hi = NN;
    while (lo < hi) { int mid = (lo + hi) >> 1; if (batch[mid] < g + 1) lo = mid + 1; else hi = mid; }
    int e = lo;
    int t = threadIdx.x;
    int f = t & 63, stripe = t >> 6;
    float a = 0.f;
    for (int r = s + stripe; r < e; r += 4)
        a += bf2f(h[(size_t)r * 512 + fc + f]);
    red[t] = a;
    __syncthreads();
    if (t < 128) red[t] += red[t + 128];
    __syncthreads();
    if (t < 64) {
        float inv = 1.0f / fmaxf((float)(e - s), 1.0f);
        gout[g * 512 + fc + t] = (red[t] + red[t + 64]) * inv;
    }
}

// ---------------------------------------------------------------------------
// Final MLP: [64,512] -> elu(@lw1^T+lb1) -> @lw2^T+lb2 -> [64,2]
// ---------------------------------------------------------------------------
__global__ __launch_bounds__(64) void mlp_kernel(const float* __restrict__ g,
                                                 const float* __restrict__ lw1,
                                                 const float* __restrict__ lb1,
                                                 const float* __restrict__ lw2,
                                                 const float* __restrict__ lb2,
                                                 float* __restrict__ outp) {
    __shared__ float gv[512];
    __shared__ float y1[32];
    int b = blockIdx.x, t = threadIdx.x;
    for (int i = t; i < 512; i += 64) gv[i] = g[b * 512 + i];
    __syncthreads();
    if (t < 32) {
        float a = lb1[t];
        for (int k = 0; k < 512; k++) a = fmaf(gv[k], lw1[t * 512 + k], a);
        y1[t] = a > 0.f ? a : (__expf(a) - 1.0f);
    }
    __syncthreads();
    if (t < 2) {
        float a = lb2[t];
        for (int k = 0; k < 32; k++) a = fmaf(y1[k], lw2[t * 32 + k], a);
        outp[b * 2 + t] = a;
    }
}

// ---------------------------------------------------------------------------
// Launch
// ---------------------------------------------------------------------------
extern "C" void kernel_launch(void* const* d_in, const int* in_sizes, int n_in,
                              void* d_out, int out_size, void* d_ws, size_t ws_size,
                              hipStream_t stream) {
    (void)in_sizes; (void)n_in; (void)out_size; (void)ws_size;
    const float* x     = (const float*)d_in[0];
    const int*   ei    = (const int*)d_in[1];
    const int*   batch = (const int*)d_in[2];
    const float* W[4]  = {(const float*)d_in[3], (const float*)d_in[7],
                          (const float*)d_in[11], (const float*)d_in[15]};
    const float* As_[4] = {(const float*)d_in[4], (const float*)d_in[8],
                           (const float*)d_in[12], (const float*)d_in[16]};
    const float* Ad_[4] = {(const float*)d_in[5], (const float*)d_in[9],
                           (const float*)d_in[13], (const float*)d_in[17]};
    const float* Bi[4]  = {(const float*)d_in[6], (const float*)d_in[10],
                           (const float*)d_in[14], (const float*)d_in[18]};
    const float* lw1 = (const float*)d_in[19];
    const float* lb1 = (const float*)d_in[20];
    const float* lw2 = (const float*)d_in[21];
    const float* lb2 = (const float*)d_in[22];
    float* out = (float*)d_out;

    // workspace layout (bf16 buffers as short)
    short* Ab = (short*)d_ws;                      // [MPAD*512] activations
    short* Hb = Ab + (size_t)MPAD * 512;           // [MPAD*512] h = act @ W^T
    short* Wb = Hb + (size_t)MPAD * 512;           // bf16 weights
    short* Wb_[4] = {Wb, Wb + 65536, Wb + 196608, Wb + 229376};
    const int wsz[4] = {65536, 131072, 32768, 65536};
    float* esb  = (float*)(Wb + 294912);           // [NN*8]
    float* edb  = esb + NN * NHEAD;                // [NN*8]
    float* gbuf = edb + NN * NHEAD;                // [64*512]
    int* row_ptr = (int*)(gbuf + NGR * 512);       // [NN+1]
    int* cursor  = row_ptr + (NN + 1);             // [NN+1]
    int* srcs    = cursor + (NN + 1);              // [NEP]
    int* bsum    = srcs + NEP;                     // [64]

    const int nblk = (NN + 1023) / 1024;           // 49

    // ---- CSR build (shared by all 4 layers)
    hipMemsetAsync(cursor, 0, NN * sizeof(int), stream);
    count_deg<<<(NEP + 255) / 256, 256, 0, stream>>>(ei, cursor);
    scan_local<<<nblk, 1024, 0, stream>>>(cursor, row_ptr, bsum, NN);
    scan_bsum<<<1, 64, 0, stream>>>(bsum, nblk);
    scan_add<<<(NN + 256) / 256, 256, 0, stream>>>(row_ptr, cursor, bsum, NN, nblk);
    scatter_edges<<<(NEP + 255) / 256, 256, 0, stream>>>(ei, cursor, srcs);

    // ---- bf16 conversions
    conv_x_pad4<<<(MPAD * 32 + 255) / 256, 256, 0, stream>>>(x, Ab);
    for (int i = 0; i < 4; i++)
        conv_f2bf<<<(wsz[i] + 255) / 256, 256, 0, stream>>>(W[i], Wb_[i], wsz[i]);

    const int rowTiles = MPAD / 128;               // 391
    int eg = (NN * NHEAD + 255) / 256;

    // ---- layer 1: 128 -> 512 (C=64), ELU
    gemm_bf<<<rowTiles * 4, 256, 0, stream>>>(Ab, Wb_[0], Hb, 128, 512, 4);
    compute_esed<64><<<eg, 256, 0, stream>>>(Hb, As_[0], Ad_[0], esb, edb);
    attn_agg<64, true><<<NN, 256, 0, stream>>>(Hb, esb, edb, row_ptr, srcs, Bi[0], Ab);

    // ---- layer 2: 512 -> 256 (C=32), ELU
    gemm_bf<<<rowTiles * 2, 256, 0, stream>>>(Ab, Wb_[1], Hb, 512, 256, 2);
    compute_esed<32><<<eg, 256, 0, stream>>>(Hb, As_[1], Ad_[1], esb, edb);
    attn_agg<32, true><<<NN, 256, 0, stream>>>(Hb, esb, edb, row_ptr, srcs, Bi[1], Ab);

    // ---- layer 3: 256 -> 128 (C=16), ELU
    gemm_bf<<<rowTiles * 1, 256, 0, stream>>>(Ab, Wb_[2], Hb, 256, 128, 1);
    compute_esed<16><<<eg, 256, 0, stream>>>(Hb, As_[2], Ad_[2], esb, edb);
    attn_agg<16, true><<<NN, 256, 0, stream>>>(Hb, esb, edb, row_ptr, srcs, Bi[2], Ab);

    // ---- layer 4: 128 -> 512 (C=64), no ELU
    gemm_bf<<<rowTiles * 4, 256, 0, stream>>>(Ab, Wb_[3], Hb, 128, 512, 4);
    compute_esed<64><<<eg, 256, 0, stream>>>(Hb, As_[3], Ad_[3], esb, edb);
    attn_agg<64, false><<<NN, 256, 0, stream>>>(Hb, esb, edb, row_ptr, srcs, Bi[3], Ab);

    // ---- pool + MLP
    pool_kernel<<<NGR * 8, 256, 0, stream>>>(Ab, batch, gbuf);
    mlp_kernel<<<NGR, 64, 0, stream>>>(gbuf, lw1, lb1, lw2, lb2, out);
}

// Round 5
// 924.411 us; speedup vs baseline: 2.0190x; 1.0832x over previous
//
#include <hip/hip_runtime.h>
#include <math.h>

// ---------------------------------------------------------------------------
// Problem constants
// ---------------------------------------------------------------------------
#define NN 50000          // nodes
#define NE 800000         // edges (before self loops)
#define NEP (NE + NN)     // edges incl self loops
#define NGR 64            // graphs
#define NHEAD 8
#define MPAD 50048        // 391 * 128

typedef short short8 __attribute__((ext_vector_type(8)));
typedef float floatx4 __attribute__((ext_vector_type(4)));
typedef unsigned uintx4 __attribute__((ext_vector_type(4)));

__device__ inline float bf2f(short s) {
    union { unsigned u; float f; } v;
    v.u = ((unsigned)(unsigned short)s) << 16;
    return v.f;
}
__device__ inline float bf2f_lo(unsigned p) {
    union { unsigned u; float f; } v; v.u = p << 16; return v.f;
}
__device__ inline float bf2f_hi(unsigned p) {
    union { unsigned u; float f; } v; v.u = p & 0xffff0000u; return v.f;
}
__device__ inline short f2bf(float f) {
    union { float f; unsigned u; } v; v.f = f;
    unsigned r = v.u + 0x7fffu + ((v.u >> 16) & 1u);   // RNE
    return (short)(r >> 16);
}

// ---------------------------------------------------------------------------
// CSR build (dst-major). Edge e<NE: src=ei[e], dst=ei[NE+e]; else self loop.
// ---------------------------------------------------------------------------
__global__ void count_deg(const int* __restrict__ ei, int* __restrict__ deg) {
    int e = blockIdx.x * 256 + threadIdx.x;
    if (e >= NEP) return;
    int d = (e < NE) ? ei[NE + e] : (e - NE);
    atomicAdd(&deg[d], 1);
}

// hierarchical scan: local 1024-wide scans -> serial scan of block sums -> add
__global__ __launch_bounds__(1024) void scan_local(const int* __restrict__ deg,
                                                   int* __restrict__ out,
                                                   int* __restrict__ bsum, int n) {
    __shared__ int sd[1024];
    int b = blockIdx.x, t = threadIdx.x;
    int i = b * 1024 + t;
    int v = (i < n) ? deg[i] : 0;
    sd[t] = v;
    __syncthreads();
    for (int off = 1; off < 1024; off <<= 1) {
        int tmp = (t >= off) ? sd[t - off] : 0;
        __syncthreads();
        sd[t] += tmp;
        __syncthreads();
    }
    if (i < n) out[i] = sd[t] - v;          // exclusive
    if (t == 1023) bsum[b] = sd[1023];
}

__global__ void scan_bsum(int* __restrict__ bsum, int nb) {
    if (threadIdx.x == 0) {
        int s = 0;
        for (int i = 0; i < nb; i++) { int v = bsum[i]; bsum[i] = s; s += v; }
        bsum[nb] = s;
    }
}

__global__ void scan_add(int* __restrict__ row_ptr, int* __restrict__ cursor,
                         const int* __restrict__ bsum, int n, int nb) {
    int i = blockIdx.x * 256 + threadIdx.x;
    if (i < n) {
        int v = row_ptr[i] + bsum[i >> 10];
        row_ptr[i] = v;
        cursor[i] = v;
    } else if (i == n) {
        row_ptr[n] = bsum[nb];
    }
}

__global__ void scatter_edges(const int* __restrict__ ei, int* __restrict__ cursor,
                              int* __restrict__ srcs) {
    int e = blockIdx.x * 256 + threadIdx.x;
    if (e >= NEP) return;
    int s, d;
    if (e < NE) { s = ei[e]; d = ei[NE + e]; }
    else        { s = e - NE; d = e - NE; }
    int pos = atomicAdd(&cursor[d], 1);
    srcs[pos] = s;
}

// ---------------------------------------------------------------------------
// fp32 -> bf16 conversions
// ---------------------------------------------------------------------------
__global__ void conv_f2bf(const float* __restrict__ in, short* __restrict__ out, int n) {
    int i = blockIdx.x * 256 + threadIdx.x;
    if (i < n) out[i] = f2bf(in[i]);
}

__global__ void conv_x_pad4(const float* __restrict__ x, short* __restrict__ xb) {
    int i = blockIdx.x * 256 + threadIdx.x;          // one float4 per thread
    if (i >= MPAD * 32) return;
    int r = i >> 5;
    short4 o;
    if (r < NN) {
        float4 v = *(const float4*)&x[(size_t)i * 4];
        o.x = f2bf(v.x); o.y = f2bf(v.y); o.z = f2bf(v.z); o.w = f2bf(v.w);
    } else {
        o.x = o.y = o.z = o.w = 0;
    }
    *(short4*)&xb[(size_t)i * 4] = o;
}

// ---------------------------------------------------------------------------
// bf16 MFMA GEMM: C[MPAD,Nc](bf16) = A[MPAD,K](bf16) @ B[Nc,K](bf16)^T
// 128x128 tile, BK=32, 4 waves, each wave 64x64 via 4x4 mfma_16x16x32_bf16.
// ---------------------------------------------------------------------------
#define LDA 40   // padded LDS row stride in shorts (80 B = 20 banks: 2-way max)
__global__ __launch_bounds__(256) void gemm_bf(const short* __restrict__ A,
                                               const short* __restrict__ B,
                                               short* __restrict__ C,
                                               int K, int Nc, int colTiles) {
    __shared__ __align__(16) short As[128 * LDA];
    __shared__ __align__(16) short Bs[128 * LDA];
    int bx = blockIdx.x % colTiles;
    int by = blockIdx.x / colTiles;
    int row0 = by * 128, col0 = bx * 128;
    int t = threadIdx.x;
    int lane = t & 63, w = t >> 6;
    int wr = (w >> 1) * 64, wc = (w & 1) * 64;
    int lrow = lane & 15, lq = lane >> 4;

    floatx4 acc[4][4];
#pragma unroll
    for (int i = 0; i < 4; i++)
#pragma unroll
        for (int j = 0; j < 4; j++) acc[i][j] = (floatx4)0.0f;

    for (int k0 = 0; k0 < K; k0 += 32) {
#pragma unroll
        for (int i = 0; i < 2; i++) {
            int chunk = t + i * 256;
            int r = chunk >> 2;
            int kc = (chunk & 3) * 8;
            *(short8*)&As[r * LDA + kc] = *(const short8*)&A[(size_t)(row0 + r) * K + k0 + kc];
            *(short8*)&Bs[r * LDA + kc] = *(const short8*)&B[(size_t)(col0 + r) * K + k0 + kc];
        }
        __syncthreads();
        short8 af[4], bfr[4];
#pragma unroll
        for (int i = 0; i < 4; i++)
            af[i] = *(const short8*)&As[(wr + i * 16 + lrow) * LDA + lq * 8];
#pragma unroll
        for (int j = 0; j < 4; j++)
            bfr[j] = *(const short8*)&Bs[(wc + j * 16 + lrow) * LDA + lq * 8];
#pragma unroll
        for (int i = 0; i < 4; i++)
#pragma unroll
            for (int j = 0; j < 4; j++)
                acc[i][j] = __builtin_amdgcn_mfma_f32_16x16x32_bf16(af[i], bfr[j], acc[i][j], 0, 0, 0);
        __syncthreads();
    }
#pragma unroll
    for (int i = 0; i < 4; i++)
#pragma unroll
        for (int j = 0; j < 4; j++)
#pragma unroll
            for (int r = 0; r < 4; r++) {
                int row = row0 + wr + i * 16 + lq * 4 + r;
                int col = col0 + wc + j * 16 + lrow;
                C[(size_t)row * Nc + col] = f2bf(acc[i][j][r]);
            }
}

// ---------------------------------------------------------------------------
// es/ed: per (node, head) dot over C channels (h bf16, a fp32).
// ---------------------------------------------------------------------------
template <int C>
__global__ void compute_esed(const short* __restrict__ h, const float* __restrict__ a_s,
                             const float* __restrict__ a_d, float* __restrict__ es,
                             float* __restrict__ ed) {
    int gid = blockIdx.x * 256 + threadIdx.x;
    if (gid >= NN * NHEAD) return;
    int n = gid >> 3, hh = gid & 7;
    const short* hr = h + (size_t)n * NHEAD * C + hh * C;
    const float* as = a_s + hh * C;
    const float* ad = a_d + hh * C;
    float s1 = 0.f, s2 = 0.f;
#pragma unroll
    for (int c = 0; c < C; c += 8) {
        short8 hv = *(const short8*)&hr[c];
#pragma unroll
        for (int j = 0; j < 8; j++) {
            float hvf = bf2f(hv[j]);
            s1 = fmaf(hvf, as[c + j], s1);
            s2 = fmaf(hvf, ad[c + j], s2);
        }
    }
    es[gid] = s1;
    ed[gid] = s2;
}

// ---------------------------------------------------------------------------
// Attention softmax + aggregation — ONE WAVE PER NODE, wave-synchronous.
// 4 nodes per 256-block. No LDS, no barriers, no degree cap.
// Phase 1/2: lane handles head lane&7, edges strided by 8; shfl_xor reduce.
// Phase 3: lane owns 8 channels; weights recomputed from es (no staging).
// ---------------------------------------------------------------------------
template <int C, bool ELU>
__global__ __launch_bounds__(256) void attn_wave(const short* __restrict__ h,
                                                 const float* __restrict__ es,
                                                 const float* __restrict__ ed,
                                                 const int* __restrict__ row_ptr,
                                                 const int* __restrict__ srcs,
                                                 const float* __restrict__ bias,
                                                 short* __restrict__ out) {
    constexpr int HC = NHEAD * C;
    constexpr int TPR = HC / 8;        // lanes covering one row: 64/32/16
    constexpr int EPI = 64 / TPR;      // edges per phase-3 iteration: 1/2/4
    int wave = threadIdx.x >> 6, lane = threadIdx.x & 63;
    int n = blockIdx.x * 4 + wave;     // grid = NN/4 exactly (NN%4==0)
    int start = row_ptr[n];
    int deg = row_ptr[n + 1] - start;
    int hh1 = lane & 7;
    float edv = ed[n * 8 + hh1];

    // phase 1: per-head max of leaky_relu(es[src]+ed[n])
    float pm = -1e30f;
    for (int idx = lane; idx < deg * 8; idx += 64) {
        int s = srcs[start + (idx >> 3)];
        float e = es[s * 8 + hh1] + edv;
        e = e > 0.f ? e : 0.2f * e;
        pm = fmaxf(pm, e);
    }
    pm = fmaxf(pm, __shfl_xor(pm, 8));
    pm = fmaxf(pm, __shfl_xor(pm, 16));
    pm = fmaxf(pm, __shfl_xor(pm, 32));

    // phase 2: per-head sum of exp(e - max)
    float ps = 0.f;
    for (int idx = lane; idx < deg * 8; idx += 64) {
        int s = srcs[start + (idx >> 3)];
        float e = es[s * 8 + hh1] + edv;
        e = e > 0.f ? e : 0.2f * e;
        ps += __expf(e - pm);
    }
    ps += __shfl_xor(ps, 8);
    ps += __shfl_xor(ps, 16);
    ps += __shfl_xor(ps, 32);
    float invd = 1.0f / ps;

    // remap per-head state to phase-3 lane roles
    int sub = lane & (TPR - 1);
    int c0 = sub * 8;
    int hh = c0 / C;                   // head of this lane's channel chunk
    float mh3 = __shfl(pm, hh);        // lanes 0..7 hold heads 0..7
    float iv3 = __shfl(invd, hh);
    float ed3 = __shfl(edv, hh);

    float acc[8];
#pragma unroll
    for (int j = 0; j < 8; j++) acc[j] = 0.f;

    // phase 3: gather 16B/lane; EPI edges in flight across the wave
    for (int k = lane / TPR; k < deg; k += EPI) {
        int s = srcs[start + k];
        float e = es[s * 8 + hh] + ed3;
        e = e > 0.f ? e : 0.2f * e;
        float wv = __expf(e - mh3) * iv3;
        uintx4 hv = *(const uintx4*)&h[(size_t)s * HC + c0];
#pragma unroll
        for (int j = 0; j < 4; j++) {
            acc[2 * j]     = fmaf(wv, bf2f_lo(hv[j]), acc[2 * j]);
            acc[2 * j + 1] = fmaf(wv, bf2f_hi(hv[j]), acc[2 * j + 1]);
        }
    }
    if (EPI >= 2) {
#pragma unroll
        for (int j = 0; j < 8; j++) acc[j] += __shfl_xor(acc[j], 32);
    }
    if (EPI == 4) {
#pragma unroll
        for (int j = 0; j < 8; j++) acc[j] += __shfl_xor(acc[j], 16);
    }
    if (lane < TPR) {
        floatx4 b0 = *(const floatx4*)&bias[c0];
        floatx4 b1 = *(const floatx4*)&bias[c0 + 4];
        float bb[8] = {b0[0], b0[1], b0[2], b0[3], b1[0], b1[1], b1[2], b1[3]};
        unsigned pk[4];
#pragma unroll
        for (int j = 0; j < 4; j++) {
            float o0 = acc[2 * j] + bb[2 * j];
            float o1 = acc[2 * j + 1] + bb[2 * j + 1];
            if (ELU) {
                o0 = o0 > 0.f ? o0 : (__expf(o0) - 1.0f);
                o1 = o1 > 0.f ? o1 : (__expf(o1) - 1.0f);
            }
            pk[j] = ((unsigned)(unsigned short)f2bf(o0)) |
                    (((unsigned)(unsigned short)f2bf(o1)) << 16);
        }
        *(uintx4*)&out[(size_t)n * HC + c0] = *(uintx4*)pk;
    }
}

// ---------------------------------------------------------------------------
// Global mean pool: 64 graphs x 8 feature-chunks of 64; 4 row stripes/block.
// ---------------------------------------------------------------------------
__global__ __launch_bounds__(256) void pool_kernel(const short* __restrict__ h,
                                                   const int* __restrict__ batch,
                                                   float* __restrict__ gout) {
    __shared__ float red[256];
    int g = blockIdx.x >> 3;
    int fc = (blockIdx.x & 7) * 64;
    int lo = 0, hi = NN;
    while (lo < hi) { int mid = (lo + hi) >> 1; if (batch[mid] < g) lo = mid + 1; else hi = mid; }
    int s = lo;
    lo = 0; hi = NN;
    while (lo < hi) { int mid = (lo + hi) >> 1; if (batch[mid] < g + 1) lo = mid + 1; else hi = mid; }
    int e = lo;
    int t = threadIdx.x;
    int f = t & 63, stripe = t >> 6;
    float a = 0.f;
    for (int r = s + stripe; r < e; r += 4)
        a += bf2f(h[(size_t)r * 512 + fc + f]);
    red[t] = a;
    __syncthreads();
    if (t < 128) red[t] += red[t + 128];
    __syncthreads();
    if (t < 64) {
        float inv = 1.0f / fmaxf((float)(e - s), 1.0f);
        gout[g * 512 + fc + t] = (red[t] + red[t + 64]) * inv;
    }
}

// ---------------------------------------------------------------------------
// Final MLP: [64,512] -> elu(@lw1^T+lb1) -> @lw2^T+lb2 -> [64,2]
// ---------------------------------------------------------------------------
__global__ __launch_bounds__(64) void mlp_kernel(const float* __restrict__ g,
                                                 const float* __restrict__ lw1,
                                                 const float* __restrict__ lb1,
                                                 const float* __restrict__ lw2,
                                                 const float* __restrict__ lb2,
                                                 float* __restrict__ outp) {
    __shared__ float gv[512];
    __shared__ float y1[32];
    int b = blockIdx.x, t = threadIdx.x;
    for (int i = t; i < 512; i += 64) gv[i] = g[b * 512 + i];
    __syncthreads();
    if (t < 32) {
        float a = lb1[t];
        for (int k = 0; k < 512; k++) a = fmaf(gv[k], lw1[t * 512 + k], a);
        y1[t] = a > 0.f ? a : (__expf(a) - 1.0f);
    }
    __syncthreads();
    if (t < 2) {
        float a = lb2[t];
        for (int k = 0; k < 32; k++) a = fmaf(y1[k], lw2[t * 32 + k], a);
        outp[b * 2 + t] = a;
    }
}

// ---------------------------------------------------------------------------
// Launch
// ---------------------------------------------------------------------------
extern "C" void kernel_launch(void* const* d_in, const int* in_sizes, int n_in,
                              void* d_out, int out_size, void* d_ws, size_t ws_size,
                              hipStream_t stream) {
    (void)in_sizes; (void)n_in; (void)out_size; (void)ws_size;
    const float* x     = (const float*)d_in[0];
    const int*   ei    = (const int*)d_in[1];
    const int*   batch = (const int*)d_in[2];
    const float* W[4]  = {(const float*)d_in[3], (const float*)d_in[7],
                          (const float*)d_in[11], (const float*)d_in[15]};
    const float* As_[4] = {(const float*)d_in[4], (const float*)d_in[8],
                           (const float*)d_in[12], (const float*)d_in[16]};
    const float* Ad_[4] = {(const float*)d_in[5], (const float*)d_in[9],
                           (const float*)d_in[13], (const float*)d_in[17]};
    const float* Bi[4]  = {(const float*)d_in[6], (const float*)d_in[10],
                           (const float*)d_in[14], (const float*)d_in[18]};
    const float* lw1 = (const float*)d_in[19];
    const float* lb1 = (const float*)d_in[20];
    const float* lw2 = (const float*)d_in[21];
    const float* lb2 = (const float*)d_in[22];
    float* out = (float*)d_out;

    // workspace layout (bf16 buffers as short)
    short* Ab = (short*)d_ws;                      // [MPAD*512] activations
    short* Hb = Ab + (size_t)MPAD * 512;           // [MPAD*512] h = act @ W^T
    short* Wb = Hb + (size_t)MPAD * 512;           // bf16 weights
    short* Wb_[4] = {Wb, Wb + 65536, Wb + 196608, Wb + 229376};
    const int wsz[4] = {65536, 131072, 32768, 65536};
    float* esb  = (float*)(Wb + 294912);           // [NN*8]
    float* edb  = esb + NN * NHEAD;                // [NN*8]
    float* gbuf = edb + NN * NHEAD;                // [64*512]
    int* row_ptr = (int*)(gbuf + NGR * 512);       // [NN+1]
    int* cursor  = row_ptr + (NN + 1);             // [NN+1]
    int* srcs    = cursor + (NN + 1);              // [NEP]
    int* bsum    = srcs + NEP;                     // [64]

    const int nblk = (NN + 1023) / 1024;           // 49

    // ---- CSR build (shared by all 4 layers)
    hipMemsetAsync(cursor, 0, NN * sizeof(int), stream);
    count_deg<<<(NEP + 255) / 256, 256, 0, stream>>>(ei, cursor);
    scan_local<<<nblk, 1024, 0, stream>>>(cursor, row_ptr, bsum, NN);
    scan_bsum<<<1, 64, 0, stream>>>(bsum, nblk);
    scan_add<<<(NN + 256) / 256, 256, 0, stream>>>(row_ptr, cursor, bsum, NN, nblk);
    scatter_edges<<<(NEP + 255) / 256, 256, 0, stream>>>(ei, cursor, srcs);

    // ---- bf16 conversions
    conv_x_pad4<<<(MPAD * 32 + 255) / 256, 256, 0, stream>>>(x, Ab);
    for (int i = 0; i < 4; i++)
        conv_f2bf<<<(wsz[i] + 255) / 256, 256, 0, stream>>>(W[i], Wb_[i], wsz[i]);

    const int rowTiles = MPAD / 128;               // 391
    int eg = (NN * NHEAD + 255) / 256;
    const int ag = NN / 4;                         // 12500 blocks, 4 nodes each

    // ---- layer 1: 128 -> 512 (C=64), ELU
    gemm_bf<<<rowTiles * 4, 256, 0, stream>>>(Ab, Wb_[0], Hb, 128, 512, 4);
    compute_esed<64><<<eg, 256, 0, stream>>>(Hb, As_[0], Ad_[0], esb, edb);
    attn_wave<64, true><<<ag, 256, 0, stream>>>(Hb, esb, edb, row_ptr, srcs, Bi[0], Ab);

    // ---- layer 2: 512 -> 256 (C=32), ELU
    gemm_bf<<<rowTiles * 2, 256, 0, stream>>>(Ab, Wb_[1], Hb, 512, 256, 2);
    compute_esed<32><<<eg, 256, 0, stream>>>(Hb, As_[1], Ad_[1], esb, edb);
    attn_wave<32, true><<<ag, 256, 0, stream>>>(Hb, esb, edb, row_ptr, srcs, Bi[1], Ab);

    // ---- layer 3: 256 -> 128 (C=16), ELU
    gemm_bf<<<rowTiles * 1, 256, 0, stream>>>(Ab, Wb_[2], Hb, 256, 128, 1);
    compute_esed<16><<<eg, 256, 0, stream>>>(Hb, As_[2], Ad_[2], esb, edb);
    attn_wave<16, true><<<ag, 256, 0, stream>>>(Hb, esb, edb, row_ptr, srcs, Bi[2], Ab);

    // ---- layer 4: 128 -> 512 (C=64), no ELU
    gemm_bf<<<rowTiles * 4, 256, 0, stream>>>(Ab, Wb_[3], Hb, 128, 512, 4);
    compute_esed<64><<<eg, 256, 0, stream>>>(Hb, As_[3], Ad_[3], esb, edb);
    attn_wave<64, false><<<ag, 256, 0, stream>>>(Hb, esb, edb, row_ptr, srcs, Bi[3], Ab);

    // ---- pool + MLP
    pool_kernel<<<NGR * 8, 256, 0, stream>>>(Ab, batch, gbuf);
    mlp_kernel<<<NGR, 64, 0, stream>>>(gbuf, lw1, lb1, lw2, lb2, out);
}

// Round 6
// 878.355 us; speedup vs baseline: 2.1248x; 1.0524x over previous
//
#include <hip/hip_runtime.h>
#include <math.h>

// ---------------------------------------------------------------------------
// Problem constants
// ---------------------------------------------------------------------------
#define NN 50000          // nodes
#define NE 800000         // edges (before self loops)
#define NEP (NE + NN)     // edges incl self loops
#define NGR 64            // graphs
#define NHEAD 8
#define MPAD 50048        // 391 * 128

typedef short short8 __attribute__((ext_vector_type(8)));
typedef float floatx4 __attribute__((ext_vector_type(4)));
typedef unsigned uintx4 __attribute__((ext_vector_type(4)));

__device__ inline float bf2f(short s) {
    union { unsigned u; float f; } v;
    v.u = ((unsigned)(unsigned short)s) << 16;
    return v.f;
}
__device__ inline float bf2f_lo(unsigned p) {
    union { unsigned u; float f; } v; v.u = p << 16; return v.f;
}
__device__ inline float bf2f_hi(unsigned p) {
    union { unsigned u; float f; } v; v.u = p & 0xffff0000u; return v.f;
}
__device__ inline short f2bf(float f) {
    union { float f; unsigned u; } v; v.f = f;
    unsigned r = v.u + 0x7fffu + ((v.u >> 16) & 1u);   // RNE
    return (short)(r >> 16);
}

// ---------------------------------------------------------------------------
// CSR build (dst-major). Edge e<NE: src=ei[e], dst=ei[NE+e]; else self loop.
// ---------------------------------------------------------------------------
__global__ void count_deg(const int* __restrict__ ei, int* __restrict__ deg) {
    int e = blockIdx.x * 256 + threadIdx.x;
    if (e >= NEP) return;
    int d = (e < NE) ? ei[NE + e] : (e - NE);
    atomicAdd(&deg[d], 1);
}

__global__ __launch_bounds__(1024) void scan_local(const int* __restrict__ deg,
                                                   int* __restrict__ out,
                                                   int* __restrict__ bsum, int n) {
    __shared__ int sd[1024];
    int b = blockIdx.x, t = threadIdx.x;
    int i = b * 1024 + t;
    int v = (i < n) ? deg[i] : 0;
    sd[t] = v;
    __syncthreads();
    for (int off = 1; off < 1024; off <<= 1) {
        int tmp = (t >= off) ? sd[t - off] : 0;
        __syncthreads();
        sd[t] += tmp;
        __syncthreads();
    }
    if (i < n) out[i] = sd[t] - v;          // exclusive
    if (t == 1023) bsum[b] = sd[1023];
}

__global__ void scan_bsum(int* __restrict__ bsum, int nb) {
    if (threadIdx.x == 0) {
        int s = 0;
        for (int i = 0; i < nb; i++) { int v = bsum[i]; bsum[i] = s; s += v; }
        bsum[nb] = s;
    }
}

__global__ void scan_add(int* __restrict__ row_ptr, int* __restrict__ cursor,
                         const int* __restrict__ bsum, int n, int nb) {
    int i = blockIdx.x * 256 + threadIdx.x;
    if (i < n) {
        int v = row_ptr[i] + bsum[i >> 10];
        row_ptr[i] = v;
        cursor[i] = v;
    } else if (i == n) {
        row_ptr[n] = bsum[nb];
    }
}

__global__ void scatter_edges(const int* __restrict__ ei, int* __restrict__ cursor,
                              int* __restrict__ srcs) {
    int e = blockIdx.x * 256 + threadIdx.x;
    if (e >= NEP) return;
    int s, d;
    if (e < NE) { s = ei[e]; d = ei[NE + e]; }
    else        { s = e - NE; d = e - NE; }
    int pos = atomicAdd(&cursor[d], 1);
    srcs[pos] = s;
}

// ---------------------------------------------------------------------------
// fp32 -> bf16 conversions
// ---------------------------------------------------------------------------
__global__ void conv_f2bf(const float* __restrict__ in, short* __restrict__ out, int n) {
    int i = blockIdx.x * 256 + threadIdx.x;
    if (i < n) out[i] = f2bf(in[i]);
}

__global__ void conv_x_pad4(const float* __restrict__ x, short* __restrict__ xb) {
    int i = blockIdx.x * 256 + threadIdx.x;          // one float4 per thread
    if (i >= MPAD * 32) return;
    int r = i >> 5;
    short4 o;
    if (r < NN) {
        float4 v = *(const float4*)&x[(size_t)i * 4];
        o.x = f2bf(v.x); o.y = f2bf(v.y); o.z = f2bf(v.z); o.w = f2bf(v.w);
    } else {
        o.x = o.y = o.z = o.w = 0;
    }
    *(short4*)&xb[(size_t)i * 4] = o;
}

// ---------------------------------------------------------------------------
// bf16 MFMA GEMM + fused es/ed epilogue.
// C[MPAD,Nc](bf16) = A[MPAD,K](bf16) @ B[Nc,K](bf16)^T, Nc = 8*C.
// 128x128 tile, BK=64, 4 waves, each wave 64x64 via 4x4 mfma_16x16x32_bf16.
// Epilogue: es[n,h] = sum_c acc(n, h*C+c)*a_s[h*C+c] (flat index = abs col),
// computed per-wave via lrow shfl_xor reductions (each wave's 64 cols cover
// whole heads since C | 64). No atomics, no extra global reads.
// ---------------------------------------------------------------------------
#define LDA 72   // LDS row stride (shorts): start banks (36R+4q)%32 -> 2-way max
template <int C>
__global__ __launch_bounds__(256) void gemm_bf(const short* __restrict__ A,
                                               const short* __restrict__ B,
                                               short* __restrict__ Cout,
                                               const float* __restrict__ a_s,
                                               const float* __restrict__ a_d,
                                               float* __restrict__ es,
                                               float* __restrict__ ed,
                                               int K) {
    constexpr int Nc = 8 * C;
    constexpr int colTiles = Nc / 128;
    constexpr int JPH = C / 16;        // j-frags per head within a wave
    constexpr int HPW = 64 / C;        // heads fully covered by one wave
    __shared__ __align__(16) short As[128 * LDA];
    __shared__ __align__(16) short Bs[128 * LDA];
    int bx = blockIdx.x % colTiles;
    int by = blockIdx.x / colTiles;
    int row0 = by * 128, col0 = bx * 128;
    int t = threadIdx.x;
    int lane = t & 63, w = t >> 6;
    int wr = (w >> 1) * 64, wc = (w & 1) * 64;
    int lrow = lane & 15, lq = lane >> 4;

    floatx4 acc[4][4];
#pragma unroll
    for (int i = 0; i < 4; i++)
#pragma unroll
        for (int j = 0; j < 4; j++) acc[i][j] = (floatx4)0.0f;

    for (int k0 = 0; k0 < K; k0 += 64) {
#pragma unroll
        for (int i = 0; i < 4; i++) {
            int chunk = t + i * 256;          // 0..1023: 128 rows x 8 kchunks
            int r = chunk >> 3;
            int kc = (chunk & 7) * 8;
            *(short8*)&As[r * LDA + kc] = *(const short8*)&A[(size_t)(row0 + r) * K + k0 + kc];
            *(short8*)&Bs[r * LDA + kc] = *(const short8*)&B[(size_t)(col0 + r) * K + k0 + kc];
        }
        __syncthreads();
#pragma unroll
        for (int kk = 0; kk < 2; kk++) {
            short8 af[4], bfr[4];
#pragma unroll
            for (int i = 0; i < 4; i++)
                af[i] = *(const short8*)&As[(wr + i * 16 + lrow) * LDA + kk * 32 + lq * 8];
#pragma unroll
            for (int j = 0; j < 4; j++)
                bfr[j] = *(const short8*)&Bs[(wc + j * 16 + lrow) * LDA + kk * 32 + lq * 8];
#pragma unroll
            for (int i = 0; i < 4; i++)
#pragma unroll
                for (int j = 0; j < 4; j++)
                    acc[i][j] = __builtin_amdgcn_mfma_f32_16x16x32_bf16(af[i], bfr[j], acc[i][j], 0, 0, 0);
        }
        __syncthreads();
    }

    // ---- C store (D layout: row=wr+i*16+lq*4+r, col=wc+j*16+lrow)
#pragma unroll
    for (int i = 0; i < 4; i++)
#pragma unroll
        for (int j = 0; j < 4; j++)
#pragma unroll
            for (int r = 0; r < 4; r++) {
                int row = row0 + wr + i * 16 + lq * 4 + r;
                int col = col0 + wc + j * 16 + lrow;
                Cout[(size_t)row * Nc + col] = f2bf(acc[i][j][r]);
            }

    // ---- fused es/ed epilogue
    float asv[4], adv[4];
#pragma unroll
    for (int j = 0; j < 4; j++) {
        int colA = col0 + wc + j * 16 + lrow;   // a_s flat [H*C] == abs col
        asv[j] = a_s[colA];
        adv[j] = a_d[colA];
    }
    int hb = (col0 + wc) / C;                   // first head this wave covers
#pragma unroll
    for (int i = 0; i < 4; i++)
#pragma unroll
        for (int r = 0; r < 4; r++) {
            float s_h[HPW], d_h[HPW];
#pragma unroll
            for (int hh = 0; hh < HPW; hh++) { s_h[hh] = 0.f; d_h[hh] = 0.f; }
#pragma unroll
            for (int j = 0; j < 4; j++) {
                s_h[j / JPH] = fmaf(acc[i][j][r], asv[j], s_h[j / JPH]);
                d_h[j / JPH] = fmaf(acc[i][j][r], adv[j], d_h[j / JPH]);
            }
#pragma unroll
            for (int hh = 0; hh < HPW; hh++) {
#pragma unroll
                for (int off = 1; off <= 8; off <<= 1) {
                    s_h[hh] += __shfl_xor(s_h[hh], off);
                    d_h[hh] += __shfl_xor(d_h[hh], off);
                }
            }
            if (lrow == 0) {
                int row = row0 + wr + i * 16 + lq * 4 + r;
                if (row < NN) {
#pragma unroll
                    for (int hh = 0; hh < HPW; hh++) {
                        es[row * 8 + hb + hh] = s_h[hh];
                        ed[row * 8 + hb + hh] = d_h[hh];
                    }
                }
            }
        }
}

// ---------------------------------------------------------------------------
// Attention softmax + aggregation — ONE WAVE PER NODE, wave-synchronous.
// 4 nodes per 256-block. No LDS, no barriers, no degree cap.
// ---------------------------------------------------------------------------
template <int C, bool ELU>
__global__ __launch_bounds__(256) void attn_wave(const short* __restrict__ h,
                                                 const float* __restrict__ es,
                                                 const float* __restrict__ ed,
                                                 const int* __restrict__ row_ptr,
                                                 const int* __restrict__ srcs,
                                                 const float* __restrict__ bias,
                                                 short* __restrict__ out) {
    constexpr int HC = NHEAD * C;
    constexpr int TPR = HC / 8;        // lanes covering one row: 64/32/16
    constexpr int EPI = 64 / TPR;      // edges per phase-3 iteration: 1/2/4
    int wave = threadIdx.x >> 6, lane = threadIdx.x & 63;
    int n = blockIdx.x * 4 + wave;     // grid = NN/4 exactly (NN%4==0)
    int start = row_ptr[n];
    int deg = row_ptr[n + 1] - start;
    int hh1 = lane & 7;
    float edv = ed[n * 8 + hh1];

    // phase 1: per-head max of leaky_relu(es[src]+ed[n])
    float pm = -1e30f;
    for (int idx = lane; idx < deg * 8; idx += 64) {
        int s = srcs[start + (idx >> 3)];
        float e = es[s * 8 + hh1] + edv;
        e = e > 0.f ? e : 0.2f * e;
        pm = fmaxf(pm, e);
    }
    pm = fmaxf(pm, __shfl_xor(pm, 8));
    pm = fmaxf(pm, __shfl_xor(pm, 16));
    pm = fmaxf(pm, __shfl_xor(pm, 32));

    // phase 2: per-head sum of exp(e - max)
    float ps = 0.f;
    for (int idx = lane; idx < deg * 8; idx += 64) {
        int s = srcs[start + (idx >> 3)];
        float e = es[s * 8 + hh1] + edv;
        e = e > 0.f ? e : 0.2f * e;
        ps += __expf(e - pm);
    }
    ps += __shfl_xor(ps, 8);
    ps += __shfl_xor(ps, 16);
    ps += __shfl_xor(ps, 32);
    float invd = 1.0f / ps;

    // remap per-head state to phase-3 lane roles
    int sub = lane & (TPR - 1);
    int c0 = sub * 8;
    int hh = c0 / C;                   // head of this lane's channel chunk
    float mh3 = __shfl(pm, hh);        // lanes 0..7 hold heads 0..7
    float iv3 = __shfl(invd, hh);
    float ed3 = __shfl(edv, hh);

    float acc[8];
#pragma unroll
    for (int j = 0; j < 8; j++) acc[j] = 0.f;

    // phase 3: gather 16B/lane; EPI edges in flight across the wave
    for (int k = lane / TPR; k < deg; k += EPI) {
        int s = srcs[start + k];
        float e = es[s * 8 + hh] + ed3;
        e = e > 0.f ? e : 0.2f * e;
        float wv = __expf(e - mh3) * iv3;
        uintx4 hv = *(const uintx4*)&h[(size_t)s * HC + c0];
#pragma unroll
        for (int j = 0; j < 4; j++) {
            acc[2 * j]     = fmaf(wv, bf2f_lo(hv[j]), acc[2 * j]);
            acc[2 * j + 1] = fmaf(wv, bf2f_hi(hv[j]), acc[2 * j + 1]);
        }
    }
    if (EPI >= 2) {
#pragma unroll
        for (int j = 0; j < 8; j++) acc[j] += __shfl_xor(acc[j], 32);
    }
    if (EPI == 4) {
#pragma unroll
        for (int j = 0; j < 8; j++) acc[j] += __shfl_xor(acc[j], 16);
    }
    if (lane < TPR) {
        floatx4 b0 = *(const floatx4*)&bias[c0];
        floatx4 b1 = *(const floatx4*)&bias[c0 + 4];
        float bb[8] = {b0[0], b0[1], b0[2], b0[3], b1[0], b1[1], b1[2], b1[3]};
        unsigned pk[4];
#pragma unroll
        for (int j = 0; j < 4; j++) {
            float o0 = acc[2 * j] + bb[2 * j];
            float o1 = acc[2 * j + 1] + bb[2 * j + 1];
            if (ELU) {
                o0 = o0 > 0.f ? o0 : (__expf(o0) - 1.0f);
                o1 = o1 > 0.f ? o1 : (__expf(o1) - 1.0f);
            }
            pk[j] = ((unsigned)(unsigned short)f2bf(o0)) |
                    (((unsigned)(unsigned short)f2bf(o1)) << 16);
        }
        *(uintx4*)&out[(size_t)n * HC + c0] = *(uintx4*)pk;
    }
}

// ---------------------------------------------------------------------------
// Global mean pool: 64 graphs x 8 feature-chunks of 64; 4 row stripes/block.
// ---------------------------------------------------------------------------
__global__ __launch_bounds__(256) void pool_kernel(const short* __restrict__ h,
                                                   const int* __restrict__ batch,
                                                   float* __restrict__ gout) {
    __shared__ float red[256];
    int g = blockIdx.x >> 3;
    int fc = (blockIdx.x & 7) * 64;
    int lo = 0, hi = NN;
    while (lo < hi) { int mid = (lo + hi) >> 1; if (batch[mid] < g) lo = mid + 1; else hi = mid; }
    int s = lo;
    lo = 0; hi = NN;
    while (lo < hi) { int mid = (lo + hi) >> 1; if (batch[mid] < g + 1) lo = mid + 1; else hi = mid; }
    int e = lo;
    int t = threadIdx.x;
    int f = t & 63, stripe = t >> 6;
    float a = 0.f;
    for (int r = s + stripe; r < e; r += 4)
        a += bf2f(h[(size_t)r * 512 + fc + f]);
    red[t] = a;
    __syncthreads();
    if (t < 128) red[t] += red[t + 128];
    __syncthreads();
    if (t < 64) {
        float inv = 1.0f / fmaxf((float)(e - s), 1.0f);
        gout[g * 512 + fc + t] = (red[t] + red[t + 64]) * inv;
    }
}

// ---------------------------------------------------------------------------
// Final MLP: [64,512] -> elu(@lw1^T+lb1) -> @lw2^T+lb2 -> [64,2]
// ---------------------------------------------------------------------------
__global__ __launch_bounds__(64) void mlp_kernel(const float* __restrict__ g,
                                                 const float* __restrict__ lw1,
                                                 const float* __restrict__ lb1,
                                                 const float* __restrict__ lw2,
                                                 const float* __restrict__ lb2,
                                                 float* __restrict__ outp) {
    __shared__ float gv[512];
    __shared__ float y1[32];
    int b = blockIdx.x, t = threadIdx.x;
    for (int i = t; i < 512; i += 64) gv[i] = g[b * 512 + i];
    __syncthreads();
    if (t < 32) {
        float a = lb1[t];
        for (int k = 0; k < 512; k++) a = fmaf(gv[k], lw1[t * 512 + k], a);
        y1[t] = a > 0.f ? a : (__expf(a) - 1.0f);
    }
    __syncthreads();
    if (t < 2) {
        float a = lb2[t];
        for (int k = 0; k < 32; k++) a = fmaf(y1[k], lw2[t * 32 + k], a);
        outp[b * 2 + t] = a;
    }
}

// ---------------------------------------------------------------------------
// Launch
// ---------------------------------------------------------------------------
extern "C" void kernel_launch(void* const* d_in, const int* in_sizes, int n_in,
                              void* d_out, int out_size, void* d_ws, size_t ws_size,
                              hipStream_t stream) {
    (void)in_sizes; (void)n_in; (void)out_size; (void)ws_size;
    const float* x     = (const float*)d_in[0];
    const int*   ei    = (const int*)d_in[1];
    const int*   batch = (const int*)d_in[2];
    const float* W[4]  = {(const float*)d_in[3], (const float*)d_in[7],
                          (const float*)d_in[11], (const float*)d_in[15]};
    const float* As_[4] = {(const float*)d_in[4], (const float*)d_in[8],
                           (const float*)d_in[12], (const float*)d_in[16]};
    const float* Ad_[4] = {(const float*)d_in[5], (const float*)d_in[9],
                           (const float*)d_in[13], (const float*)d_in[17]};
    const float* Bi[4]  = {(const float*)d_in[6], (const float*)d_in[10],
                           (const float*)d_in[14], (const float*)d_in[18]};
    const float* lw1 = (const float*)d_in[19];
    const float* lb1 = (const float*)d_in[20];
    const float* lw2 = (const float*)d_in[21];
    const float* lb2 = (const float*)d_in[22];
    float* out = (float*)d_out;

    // workspace layout (bf16 buffers as short)
    short* Ab = (short*)d_ws;                      // [MPAD*512] activations
    short* Hb = Ab + (size_t)MPAD * 512;           // [MPAD*512] h = act @ W^T
    short* Wb = Hb + (size_t)MPAD * 512;           // bf16 weights
    short* Wb_[4] = {Wb, Wb + 65536, Wb + 196608, Wb + 229376};
    const int wsz[4] = {65536, 131072, 32768, 65536};
    float* esb  = (float*)(Wb + 294912);           // [NN*8]
    float* edb  = esb + NN * NHEAD;                // [NN*8]
    float* gbuf = edb + NN * NHEAD;                // [64*512]
    int* row_ptr = (int*)(gbuf + NGR * 512);       // [NN+1]
    int* cursor  = row_ptr + (NN + 1);             // [NN+1]
    int* srcs    = cursor + (NN + 1);              // [NEP]
    int* bsum    = srcs + NEP;                     // [64]

    const int nblk = (NN + 1023) / 1024;           // 49

    // ---- CSR build (shared by all 4 layers)
    hipMemsetAsync(cursor, 0, NN * sizeof(int), stream);
    count_deg<<<(NEP + 255) / 256, 256, 0, stream>>>(ei, cursor);
    scan_local<<<nblk, 1024, 0, stream>>>(cursor, row_ptr, bsum, NN);
    scan_bsum<<<1, 64, 0, stream>>>(bsum, nblk);
    scan_add<<<(NN + 256) / 256, 256, 0, stream>>>(row_ptr, cursor, bsum, NN, nblk);
    scatter_edges<<<(NEP + 255) / 256, 256, 0, stream>>>(ei, cursor, srcs);

    // ---- bf16 conversions
    conv_x_pad4<<<(MPAD * 32 + 255) / 256, 256, 0, stream>>>(x, Ab);
    for (int i = 0; i < 4; i++)
        conv_f2bf<<<(wsz[i] + 255) / 256, 256, 0, stream>>>(W[i], Wb_[i], wsz[i]);

    const int rowTiles = MPAD / 128;               // 391
    const int ag = NN / 4;                         // 12500 blocks, 4 nodes each

    // ---- layer 1: 128 -> 512 (C=64), ELU
    gemm_bf<64><<<rowTiles * 4, 256, 0, stream>>>(Ab, Wb_[0], Hb, As_[0], Ad_[0], esb, edb, 128);
    attn_wave<64, true><<<ag, 256, 0, stream>>>(Hb, esb, edb, row_ptr, srcs, Bi[0], Ab);

    // ---- layer 2: 512 -> 256 (C=32), ELU
    gemm_bf<32><<<rowTiles * 2, 256, 0, stream>>>(Ab, Wb_[1], Hb, As_[1], Ad_[1], esb, edb, 512);
    attn_wave<32, true><<<ag, 256, 0, stream>>>(Hb, esb, edb, row_ptr, srcs, Bi[1], Ab);

    // ---- layer 3: 256 -> 128 (C=16), ELU
    gemm_bf<16><<<rowTiles * 1, 256, 0, stream>>>(Ab, Wb_[2], Hb, As_[2], Ad_[2], esb, edb, 256);
    attn_wave<16, true><<<ag, 256, 0, stream>>>(Hb, esb, edb, row_ptr, srcs, Bi[2], Ab);

    // ---- layer 4: 128 -> 512 (C=64), no ELU
    gemm_bf<64><<<rowTiles * 4, 256, 0, stream>>>(Ab, Wb_[3], Hb, As_[3], Ad_[3], esb, edb, 128);
    attn_wave<64, false><<<ag, 256, 0, stream>>>(Hb, esb, edb, row_ptr, srcs, Bi[3], Ab);

    // ---- pool + MLP
    pool_kernel<<<NGR * 8, 256, 0, stream>>>(Ab, batch, gbuf);
    mlp_kernel<<<NGR, 64, 0, stream>>>(gbuf, lw1, lb1, lw2, lb2, out);
}

// Round 7
// 813.240 us; speedup vs baseline: 2.2950x; 1.0801x over previous
//
#include <hip/hip_runtime.h>
#include <math.h>

// ---------------------------------------------------------------------------
// Problem constants
// ---------------------------------------------------------------------------
#define NN 50000          // nodes
#define NE 800000         // edges (before self loops)
#define NEP (NE + NN)     // edges incl self loops
#define NGR 64            // graphs
#define NHEAD 8
#define MPAD 50048        // 391 * 128

typedef short short8 __attribute__((ext_vector_type(8)));
typedef float floatx4 __attribute__((ext_vector_type(4)));
typedef unsigned uintx4 __attribute__((ext_vector_type(4)));

__device__ inline float bf2f(short s) {
    union { unsigned u; float f; } v;
    v.u = ((unsigned)(unsigned short)s) << 16;
    return v.f;
}
__device__ inline float bf2f_lo(unsigned p) {
    union { unsigned u; float f; } v; v.u = p << 16; return v.f;
}
__device__ inline float bf2f_hi(unsigned p) {
    union { unsigned u; float f; } v; v.u = p & 0xffff0000u; return v.f;
}
__device__ inline short f2bf(float f) {
    union { float f; unsigned u; } v; v.f = f;
    unsigned r = v.u + 0x7fffu + ((v.u >> 16) & 1u);   // RNE
    return (short)(r >> 16);
}

// async global->LDS, 16 B per lane; lds dst = wave-uniform base + lane*16
__device__ inline void gl_lds16(const short* g, short* l) {
    __builtin_amdgcn_global_load_lds(
        (const __attribute__((address_space(1))) unsigned int*)g,
        (__attribute__((address_space(3))) unsigned int*)l, 16, 0, 0);
}

// ---------------------------------------------------------------------------
// CSR build (dst-major). Edge e<NE: src=ei[e], dst=ei[NE+e]; else self loop.
// ---------------------------------------------------------------------------
__global__ void count_deg(const int* __restrict__ ei, int* __restrict__ deg) {
    int e = blockIdx.x * 256 + threadIdx.x;
    if (e >= NEP) return;
    int d = (e < NE) ? ei[NE + e] : (e - NE);
    atomicAdd(&deg[d], 1);
}

__global__ __launch_bounds__(1024) void scan_local(const int* __restrict__ deg,
                                                   int* __restrict__ out,
                                                   int* __restrict__ bsum, int n) {
    __shared__ int sd[1024];
    int b = blockIdx.x, t = threadIdx.x;
    int i = b * 1024 + t;
    int v = (i < n) ? deg[i] : 0;
    sd[t] = v;
    __syncthreads();
    for (int off = 1; off < 1024; off <<= 1) {
        int tmp = (t >= off) ? sd[t - off] : 0;
        __syncthreads();
        sd[t] += tmp;
        __syncthreads();
    }
    if (i < n) out[i] = sd[t] - v;          // exclusive
    if (t == 1023) bsum[b] = sd[1023];
}

__global__ void scan_bsum(int* __restrict__ bsum, int nb) {
    if (threadIdx.x == 0) {
        int s = 0;
        for (int i = 0; i < nb; i++) { int v = bsum[i]; bsum[i] = s; s += v; }
        bsum[nb] = s;
    }
}

__global__ void scan_add(int* __restrict__ row_ptr, int* __restrict__ cursor,
                         const int* __restrict__ bsum, int n, int nb) {
    int i = blockIdx.x * 256 + threadIdx.x;
    if (i < n) {
        int v = row_ptr[i] + bsum[i >> 10];
        row_ptr[i] = v;
        cursor[i] = v;
    } else if (i == n) {
        row_ptr[n] = bsum[nb];
    }
}

__global__ void scatter_edges(const int* __restrict__ ei, int* __restrict__ cursor,
                              int* __restrict__ srcs) {
    int e = blockIdx.x * 256 + threadIdx.x;
    if (e >= NEP) return;
    int s, d;
    if (e < NE) { s = ei[e]; d = ei[NE + e]; }
    else        { s = e - NE; d = e - NE; }
    int pos = atomicAdd(&cursor[d], 1);
    srcs[pos] = s;
}

// ---------------------------------------------------------------------------
// fp32 -> bf16 conversions
// ---------------------------------------------------------------------------
__global__ void conv_f2bf(const float* __restrict__ in, short* __restrict__ out, int n) {
    int i = blockIdx.x * 256 + threadIdx.x;
    if (i < n) out[i] = f2bf(in[i]);
}

__global__ void conv_x_pad4(const float* __restrict__ x, short* __restrict__ xb) {
    int i = blockIdx.x * 256 + threadIdx.x;          // one float4 per thread
    if (i >= MPAD * 32) return;
    int r = i >> 5;
    short4 o;
    if (r < NN) {
        float4 v = *(const float4*)&x[(size_t)i * 4];
        o.x = f2bf(v.x); o.y = f2bf(v.y); o.z = f2bf(v.z); o.w = f2bf(v.w);
    } else {
        o.x = o.y = o.z = o.w = 0;
    }
    *(short4*)&xb[(size_t)i * 4] = o;
}

// ---------------------------------------------------------------------------
// bf16 MFMA GEMM + fused es/ed epilogue, async global_load_lds staging.
// C[MPAD,Nc](bf16) = A[MPAD,K](bf16) @ B[Nc,K](bf16)^T, Nc = 8*C.
// 128x128 tile, BK=64, 4 waves, each 64x64 via 4x4 mfma_16x16x32_bf16.
// LDS layout XOR-swizzled (slot = kc8 ^ (row&7)), unpadded 128x64 shorts —
// DMA-compatible (lane-contiguous 1KB per issue) and conflict-free b128 reads.
// ---------------------------------------------------------------------------
template <int C>
__global__ __launch_bounds__(256) void gemm_bf(const short* __restrict__ A,
                                               const short* __restrict__ B,
                                               short* __restrict__ Cout,
                                               const float* __restrict__ a_s,
                                               const float* __restrict__ a_d,
                                               float* __restrict__ es,
                                               float* __restrict__ ed,
                                               int K) {
    constexpr int Nc = 8 * C;
    constexpr int colTiles = Nc / 128;
    constexpr int JPH = C / 16;        // j-frags per head within a wave
    constexpr int HPW = 64 / C;        // heads fully covered by one wave
    __shared__ __align__(16) short As[128 * 64];
    __shared__ __align__(16) short Bs[128 * 64];
    int bx = blockIdx.x % colTiles;
    int by = blockIdx.x / colTiles;
    int row0 = by * 128, col0 = bx * 128;
    int t = threadIdx.x;
    int lane = t & 63, w = t >> 6;
    int wr = (w >> 1) * 64, wc = (w & 1) * 64;
    int lrow = lane & 15, lq = lane >> 4;

    // staging roles: wave w stages rows [w*32, w*32+32), 4 issues of 8 rows
    int srow = lane >> 3;              // 0..7 row within group
    int kcsrc = (lane & 7) ^ srow;     // swizzled source k-chunk

    floatx4 acc[4][4];
#pragma unroll
    for (int i = 0; i < 4; i++)
#pragma unroll
        for (int j = 0; j < 4; j++) acc[i][j] = (floatx4)0.0f;

    for (int k0 = 0; k0 < K; k0 += 64) {
#pragma unroll
        for (int it = 0; it < 4; it++) {
            int r0 = w * 32 + it * 8;
            int r = r0 + srow;
            gl_lds16(&A[(size_t)(row0 + r) * K + k0 + kcsrc * 8], &As[r0 * 64]);
            gl_lds16(&B[(size_t)(col0 + r) * K + k0 + kcsrc * 8], &Bs[r0 * 64]);
        }
        __syncthreads();
#pragma unroll
        for (int kk = 0; kk < 2; kk++) {
            int slot = (kk * 4 + lq) ^ (lrow & 7);
            short8 af[4], bfr[4];
#pragma unroll
            for (int i = 0; i < 4; i++)
                af[i] = *(const short8*)&As[(wr + i * 16 + lrow) * 64 + slot * 8];
#pragma unroll
            for (int j = 0; j < 4; j++)
                bfr[j] = *(const short8*)&Bs[(wc + j * 16 + lrow) * 64 + slot * 8];
#pragma unroll
            for (int i = 0; i < 4; i++)
#pragma unroll
                for (int j = 0; j < 4; j++)
                    acc[i][j] = __builtin_amdgcn_mfma_f32_16x16x32_bf16(af[i], bfr[j], acc[i][j], 0, 0, 0);
        }
        __syncthreads();
    }

    // ---- C store (D layout: row=wr+i*16+lq*4+r, col=wc+j*16+lrow)
#pragma unroll
    for (int i = 0; i < 4; i++)
#pragma unroll
        for (int j = 0; j < 4; j++)
#pragma unroll
            for (int r = 0; r < 4; r++) {
                int row = row0 + wr + i * 16 + lq * 4 + r;
                int col = col0 + wc + j * 16 + lrow;
                Cout[(size_t)row * Nc + col] = f2bf(acc[i][j][r]);
            }

    // ---- fused es/ed epilogue (a_s flat [H*C] == abs col index)
    float asv[4], adv[4];
#pragma unroll
    for (int j = 0; j < 4; j++) {
        int colA = col0 + wc + j * 16 + lrow;
        asv[j] = a_s[colA];
        adv[j] = a_d[colA];
    }
    int hb = (col0 + wc) / C;                   // first head this wave covers
#pragma unroll
    for (int i = 0; i < 4; i++)
#pragma unroll
        for (int r = 0; r < 4; r++) {
            float s_h[HPW], d_h[HPW];
#pragma unroll
            for (int hh = 0; hh < HPW; hh++) { s_h[hh] = 0.f; d_h[hh] = 0.f; }
#pragma unroll
            for (int j = 0; j < 4; j++) {
                s_h[j / JPH] = fmaf(acc[i][j][r], asv[j], s_h[j / JPH]);
                d_h[j / JPH] = fmaf(acc[i][j][r], adv[j], d_h[j / JPH]);
            }
#pragma unroll
            for (int hh = 0; hh < HPW; hh++) {
#pragma unroll
                for (int off = 1; off <= 8; off <<= 1) {
                    s_h[hh] += __shfl_xor(s_h[hh], off);
                    d_h[hh] += __shfl_xor(d_h[hh], off);
                }
            }
            if (lrow == 0) {
                int row = row0 + wr + i * 16 + lq * 4 + r;
                if (row < NN) {
#pragma unroll
                    for (int hh = 0; hh < HPW; hh++) {
                        es[row * 8 + hb + hh] = s_h[hh];
                        ed[row * 8 + hb + hh] = d_h[hh];
                    }
                }
            }
        }
}

// ---------------------------------------------------------------------------
// Attention — ONE WAVE PER NODE, wave-synchronous, 2 passes.
// Pass 1: online softmax (running max + rescaled sum) — single edge sweep.
// Pass 2: weighted gather, 16B/lane.
// ---------------------------------------------------------------------------
template <int C, bool ELU>
__global__ __launch_bounds__(256) void attn_wave(const short* __restrict__ h,
                                                 const float* __restrict__ es,
                                                 const float* __restrict__ ed,
                                                 const int* __restrict__ row_ptr,
                                                 const int* __restrict__ srcs,
                                                 const float* __restrict__ bias,
                                                 short* __restrict__ out) {
    constexpr int HC = NHEAD * C;
    constexpr int TPR = HC / 8;        // lanes covering one row: 64/32/16
    constexpr int EPI = 64 / TPR;      // edges per pass-2 iteration: 1/2/4
    int wave = threadIdx.x >> 6, lane = threadIdx.x & 63;
    int n = blockIdx.x * 4 + wave;     // grid = NN/4 exactly (NN%4==0)
    int start = row_ptr[n];
    int deg = row_ptr[n + 1] - start;
    int hh1 = lane & 7;
    float edv = ed[n * 8 + hh1];

    // pass 1: online per-head softmax stats over leaky_relu(es[src]+ed[n])
    float pm = -1e30f, ps = 0.f;
    for (int idx = lane; idx < deg * 8; idx += 64) {
        int s = srcs[start + (idx >> 3)];
        float e = es[s * 8 + hh1] + edv;
        e = e > 0.f ? e : 0.2f * e;
        float mn = fmaxf(pm, e);
        ps = ps * __expf(pm - mn) + __expf(e - mn);
        pm = mn;
    }
#pragma unroll
    for (int off = 8; off <= 32; off <<= 1) {
        float mo = __shfl_xor(pm, off);
        float so = __shfl_xor(ps, off);
        float mn = fmaxf(pm, mo);
        ps = ps * __expf(pm - mn) + so * __expf(mo - mn);
        pm = mn;
    }
    float invd = 1.0f / ps;

    // remap per-head state to pass-2 lane roles
    int sub = lane & (TPR - 1);
    int c0 = sub * 8;
    int hh = c0 / C;                   // head of this lane's channel chunk
    float mh3 = __shfl(pm, hh);        // lanes 0..7 hold heads 0..7
    float iv3 = __shfl(invd, hh);
    float ed3 = __shfl(edv, hh);

    float acc[8];
#pragma unroll
    for (int j = 0; j < 8; j++) acc[j] = 0.f;

    // pass 2: gather 16B/lane; EPI edges in flight across the wave
#pragma unroll 2
    for (int k = lane / TPR; k < deg; k += EPI) {
        int s = srcs[start + k];
        float e = es[s * 8 + hh] + ed3;
        e = e > 0.f ? e : 0.2f * e;
        float wv = __expf(e - mh3) * iv3;
        uintx4 hv = *(const uintx4*)&h[(size_t)s * HC + c0];
#pragma unroll
        for (int j = 0; j < 4; j++) {
            acc[2 * j]     = fmaf(wv, bf2f_lo(hv[j]), acc[2 * j]);
            acc[2 * j + 1] = fmaf(wv, bf2f_hi(hv[j]), acc[2 * j + 1]);
        }
    }
    if (EPI >= 2) {
#pragma unroll
        for (int j = 0; j < 8; j++) acc[j] += __shfl_xor(acc[j], 32);
    }
    if (EPI == 4) {
#pragma unroll
        for (int j = 0; j < 8; j++) acc[j] += __shfl_xor(acc[j], 16);
    }
    if (lane < TPR) {
        floatx4 b0 = *(const floatx4*)&bias[c0];
        floatx4 b1 = *(const floatx4*)&bias[c0 + 4];
        float bb[8] = {b0[0], b0[1], b0[2], b0[3], b1[0], b1[1], b1[2], b1[3]};
        unsigned pk[4];
#pragma unroll
        for (int j = 0; j < 4; j++) {
            float o0 = acc[2 * j] + bb[2 * j];
            float o1 = acc[2 * j + 1] + bb[2 * j + 1];
            if (ELU) {
                o0 = o0 > 0.f ? o0 : (__expf(o0) - 1.0f);
                o1 = o1 > 0.f ? o1 : (__expf(o1) - 1.0f);
            }
            pk[j] = ((unsigned)(unsigned short)f2bf(o0)) |
                    (((unsigned)(unsigned short)f2bf(o1)) << 16);
        }
        *(uintx4*)&out[(size_t)n * HC + c0] = *(uintx4*)pk;
    }
}

// ---------------------------------------------------------------------------
// Global mean pool: 64 graphs x 8 feature-chunks of 64; 4 row stripes/block.
// ---------------------------------------------------------------------------
__global__ __launch_bounds__(256) void pool_kernel(const short* __restrict__ h,
                                                   const int* __restrict__ batch,
                                                   float* __restrict__ gout) {
    __shared__ float red[256];
    int g = blockIdx.x >> 3;
    int fc = (blockIdx.x & 7) * 64;
    int lo = 0, hi = NN;
    while (lo < hi) { int mid = (lo + hi) >> 1; if (batch[mid] < g) lo = mid + 1; else hi = mid; }
    int s = lo;
    lo = 0; hi = NN;
    while (lo < hi) { int mid = (lo + hi) >> 1; if (batch[mid] < g + 1) lo = mid + 1; else hi = mid; }
    int e = lo;
    int t = threadIdx.x;
    int f = t & 63, stripe = t >> 6;
    float a = 0.f;
    for (int r = s + stripe; r < e; r += 4)
        a += bf2f(h[(size_t)r * 512 + fc + f]);
    red[t] = a;
    __syncthreads();
    if (t < 128) red[t] += red[t + 128];
    __syncthreads();
    if (t < 64) {
        float inv = 1.0f / fmaxf((float)(e - s), 1.0f);
        gout[g * 512 + fc + t] = (red[t] + red[t + 64]) * inv;
    }
}

// ---------------------------------------------------------------------------
// Final MLP: [64,512] -> elu(@lw1^T+lb1) -> @lw2^T+lb2 -> [64,2]
// ---------------------------------------------------------------------------
__global__ __launch_bounds__(64) void mlp_kernel(const float* __restrict__ g,
                                                 const float* __restrict__ lw1,
                                                 const float* __restrict__ lb1,
                                                 const float* __restrict__ lw2,
                                                 const float* __restrict__ lb2,
                                                 float* __restrict__ outp) {
    __shared__ float gv[512];
    __shared__ float y1[32];
    int b = blockIdx.x, t = threadIdx.x;
    for (int i = t; i < 512; i += 64) gv[i] = g[b * 512 + i];
    __syncthreads();
    if (t < 32) {
        float a = lb1[t];
        for (int k = 0; k < 512; k++) a = fmaf(gv[k], lw1[t * 512 + k], a);
        y1[t] = a > 0.f ? a : (__expf(a) - 1.0f);
    }
    __syncthreads();
    if (t < 2) {
        float a = lb2[t];
        for (int k = 0; k < 32; k++) a = fmaf(y1[k], lw2[t * 32 + k], a);
        outp[b * 2 + t] = a;
    }
}

// ---------------------------------------------------------------------------
// Launch
// ---------------------------------------------------------------------------
extern "C" void kernel_launch(void* const* d_in, const int* in_sizes, int n_in,
                              void* d_out, int out_size, void* d_ws, size_t ws_size,
                              hipStream_t stream) {
    (void)in_sizes; (void)n_in; (void)out_size; (void)ws_size;
    const float* x     = (const float*)d_in[0];
    const int*   ei    = (const int*)d_in[1];
    const int*   batch = (const int*)d_in[2];
    const float* W[4]  = {(const float*)d_in[3], (const float*)d_in[7],
                          (const float*)d_in[11], (const float*)d_in[15]};
    const float* As_[4] = {(const float*)d_in[4], (const float*)d_in[8],
                           (const float*)d_in[12], (const float*)d_in[16]};
    const float* Ad_[4] = {(const float*)d_in[5], (const float*)d_in[9],
                           (const float*)d_in[13], (const float*)d_in[17]};
    const float* Bi[4]  = {(const float*)d_in[6], (const float*)d_in[10],
                           (const float*)d_in[14], (const float*)d_in[18]};
    const float* lw1 = (const float*)d_in[19];
    const float* lb1 = (const float*)d_in[20];
    const float* lw2 = (const float*)d_in[21];
    const float* lb2 = (const float*)d_in[22];
    float* out = (float*)d_out;

    // workspace layout (bf16 buffers as short)
    short* Ab = (short*)d_ws;                      // [MPAD*512] activations
    short* Hb = Ab + (size_t)MPAD * 512;           // [MPAD*512] h = act @ W^T
    short* Wb = Hb + (size_t)MPAD * 512;           // bf16 weights
    short* Wb_[4] = {Wb, Wb + 65536, Wb + 196608, Wb + 229376};
    const int wsz[4] = {65536, 131072, 32768, 65536};
    float* esb  = (float*)(Wb + 294912);           // [NN*8]
    float* edb  = esb + NN * NHEAD;                // [NN*8]
    float* gbuf = edb + NN * NHEAD;                // [64*512]
    int* row_ptr = (int*)(gbuf + NGR * 512);       // [NN+1]
    int* cursor  = row_ptr + (NN + 1);             // [NN+1]
    int* srcs    = cursor + (NN + 1);              // [NEP]
    int* bsum    = srcs + NEP;                     // [64]

    const int nblk = (NN + 1023) / 1024;           // 49

    // ---- CSR build (shared by all 4 layers)
    hipMemsetAsync(cursor, 0, NN * sizeof(int), stream);
    count_deg<<<(NEP + 255) / 256, 256, 0, stream>>>(ei, cursor);
    scan_local<<<nblk, 1024, 0, stream>>>(cursor, row_ptr, bsum, NN);
    scan_bsum<<<1, 64, 0, stream>>>(bsum, nblk);
    scan_add<<<(NN + 256) / 256, 256, 0, stream>>>(row_ptr, cursor, bsum, NN, nblk);
    scatter_edges<<<(NEP + 255) / 256, 256, 0, stream>>>(ei, cursor, srcs);

    // ---- bf16 conversions
    conv_x_pad4<<<(MPAD * 32 + 255) / 256, 256, 0, stream>>>(x, Ab);
    for (int i = 0; i < 4; i++)
        conv_f2bf<<<(wsz[i] + 255) / 256, 256, 0, stream>>>(W[i], Wb_[i], wsz[i]);

    const int rowTiles = MPAD / 128;               // 391
    const int ag = NN / 4;                         // 12500 blocks, 4 nodes each

    // ---- layer 1: 128 -> 512 (C=64), ELU
    gemm_bf<64><<<rowTiles * 4, 256, 0, stream>>>(Ab, Wb_[0], Hb, As_[0], Ad_[0], esb, edb, 128);
    attn_wave<64, true><<<ag, 256, 0, stream>>>(Hb, esb, edb, row_ptr, srcs, Bi[0], Ab);

    // ---- layer 2: 512 -> 256 (C=32), ELU
    gemm_bf<32><<<rowTiles * 2, 256, 0, stream>>>(Ab, Wb_[1], Hb, As_[1], Ad_[1], esb, edb, 512);
    attn_wave<32, true><<<ag, 256, 0, stream>>>(Hb, esb, edb, row_ptr, srcs, Bi[1], Ab);

    // ---- layer 3: 256 -> 128 (C=16), ELU
    gemm_bf<16><<<rowTiles * 1, 256, 0, stream>>>(Ab, Wb_[2], Hb, As_[2], Ad_[2], esb, edb, 256);
    attn_wave<16, true><<<ag, 256, 0, stream>>>(Hb, esb, edb, row_ptr, srcs, Bi[2], Ab);

    // ---- layer 4: 128 -> 512 (C=64), no ELU
    gemm_bf<64><<<rowTiles * 4, 256, 0, stream>>>(Ab, Wb_[3], Hb, As_[3], Ad_[3], esb, edb, 128);
    attn_wave<64, false><<<ag, 256, 0, stream>>>(Hb, esb, edb, row_ptr, srcs, Bi[3], Ab);

    // ---- pool + MLP
    pool_kernel<<<NGR * 8, 256, 0, stream>>>(Ab, batch, gbuf);
    mlp_kernel<<<NGR, 64, 0, stream>>>(gbuf, lw1, lb1, lw2, lb2, out);
}

// Round 8
// 794.915 us; speedup vs baseline: 2.3479x; 1.0231x over previous
//
#include <hip/hip_runtime.h>
#include <math.h>

// ---------------------------------------------------------------------------
// Problem constants
// ---------------------------------------------------------------------------
#define NN 50000          // nodes
#define NE 800000         // edges (before self loops)
#define NEP (NE + NN)     // edges incl self loops
#define NGR 64            // graphs
#define NHEAD 8
#define MPAD 50048        // 391 * 128
#define DEG_CAPW 128      // per-wave LDS alpha slab (edges); fallback beyond

typedef short short8 __attribute__((ext_vector_type(8)));
typedef float floatx4 __attribute__((ext_vector_type(4)));
typedef unsigned uintx4 __attribute__((ext_vector_type(4)));

__device__ inline float bf2f(short s) {
    union { unsigned u; float f; } v;
    v.u = ((unsigned)(unsigned short)s) << 16;
    return v.f;
}
__device__ inline float bf2f_lo(unsigned p) {
    union { unsigned u; float f; } v; v.u = p << 16; return v.f;
}
__device__ inline float bf2f_hi(unsigned p) {
    union { unsigned u; float f; } v; v.u = p & 0xffff0000u; return v.f;
}
__device__ inline short f2bf(float f) {
    union { float f; unsigned u; } v; v.f = f;
    unsigned r = v.u + 0x7fffu + ((v.u >> 16) & 1u);   // RNE
    return (short)(r >> 16);
}

// async global->LDS, 16 B per lane; lds dst = wave-uniform base + lane*16
__device__ inline void gl_lds16(const short* g, short* l) {
    __builtin_amdgcn_global_load_lds(
        (const __attribute__((address_space(1))) unsigned int*)g,
        (__attribute__((address_space(3))) unsigned int*)l, 16, 0, 0);
}

// ---------------------------------------------------------------------------
// CSR build (dst-major). Edge e<NE: src=ei[e], dst=ei[NE+e]; else self loop.
// ---------------------------------------------------------------------------
__global__ void count_deg(const int* __restrict__ ei, int* __restrict__ deg) {
    int e = blockIdx.x * 256 + threadIdx.x;
    if (e >= NEP) return;
    int d = (e < NE) ? ei[NE + e] : (e - NE);
    atomicAdd(&deg[d], 1);
}

__global__ __launch_bounds__(1024) void scan_local(const int* __restrict__ deg,
                                                   int* __restrict__ out,
                                                   int* __restrict__ bsum, int n) {
    __shared__ int sd[1024];
    int b = blockIdx.x, t = threadIdx.x;
    int i = b * 1024 + t;
    int v = (i < n) ? deg[i] : 0;
    sd[t] = v;
    __syncthreads();
    for (int off = 1; off < 1024; off <<= 1) {
        int tmp = (t >= off) ? sd[t - off] : 0;
        __syncthreads();
        sd[t] += tmp;
        __syncthreads();
    }
    if (i < n) out[i] = sd[t] - v;          // exclusive
    if (t == 1023) bsum[b] = sd[1023];
}

__global__ void scan_bsum(int* __restrict__ bsum, int nb) {
    if (threadIdx.x == 0) {
        int s = 0;
        for (int i = 0; i < nb; i++) { int v = bsum[i]; bsum[i] = s; s += v; }
        bsum[nb] = s;
    }
}

__global__ void scan_add(int* __restrict__ row_ptr, int* __restrict__ cursor,
                         const int* __restrict__ bsum, int n, int nb) {
    int i = blockIdx.x * 256 + threadIdx.x;
    if (i < n) {
        int v = row_ptr[i] + bsum[i >> 10];
        row_ptr[i] = v;
        cursor[i] = v;
    } else if (i == n) {
        row_ptr[n] = bsum[nb];
    }
}

__global__ void scatter_edges(const int* __restrict__ ei, int* __restrict__ cursor,
                              int* __restrict__ srcs) {
    int e = blockIdx.x * 256 + threadIdx.x;
    if (e >= NEP) return;
    int s, d;
    if (e < NE) { s = ei[e]; d = ei[NE + e]; }
    else        { s = e - NE; d = e - NE; }
    int pos = atomicAdd(&cursor[d], 1);
    srcs[pos] = s;
}

// ---------------------------------------------------------------------------
// fp32 -> bf16 conversions
// ---------------------------------------------------------------------------
__global__ void conv_f2bf(const float* __restrict__ in, short* __restrict__ out, int n) {
    int i = blockIdx.x * 256 + threadIdx.x;
    if (i < n) out[i] = f2bf(in[i]);
}

__global__ void conv_x_pad4(const float* __restrict__ x, short* __restrict__ xb) {
    int i = blockIdx.x * 256 + threadIdx.x;          // one float4 per thread
    if (i >= MPAD * 32) return;
    int r = i >> 5;
    short4 o;
    if (r < NN) {
        float4 v = *(const float4*)&x[(size_t)i * 4];
        o.x = f2bf(v.x); o.y = f2bf(v.y); o.z = f2bf(v.z); o.w = f2bf(v.w);
    } else {
        o.x = o.y = o.z = o.w = 0;
    }
    *(short4*)&xb[(size_t)i * 4] = o;
}

// ---------------------------------------------------------------------------
// bf16 MFMA GEMM + fused es/ed epilogue, async global_load_lds staging.
// (unchanged from R7 — XOR-swizzled unpadded LDS, BK=64, 128x128 tile)
// ---------------------------------------------------------------------------
template <int C>
__global__ __launch_bounds__(256) void gemm_bf(const short* __restrict__ A,
                                               const short* __restrict__ B,
                                               short* __restrict__ Cout,
                                               const float* __restrict__ a_s,
                                               const float* __restrict__ a_d,
                                               float* __restrict__ es,
                                               float* __restrict__ ed,
                                               int K) {
    constexpr int Nc = 8 * C;
    constexpr int colTiles = Nc / 128;
    constexpr int JPH = C / 16;        // j-frags per head within a wave
    constexpr int HPW = 64 / C;        // heads fully covered by one wave
    __shared__ __align__(16) short As[128 * 64];
    __shared__ __align__(16) short Bs[128 * 64];
    int bx = blockIdx.x % colTiles;
    int by = blockIdx.x / colTiles;
    int row0 = by * 128, col0 = bx * 128;
    int t = threadIdx.x;
    int lane = t & 63, w = t >> 6;
    int wr = (w >> 1) * 64, wc = (w & 1) * 64;
    int lrow = lane & 15, lq = lane >> 4;

    int srow = lane >> 3;              // 0..7 row within group
    int kcsrc = (lane & 7) ^ srow;     // swizzled source k-chunk

    floatx4 acc[4][4];
#pragma unroll
    for (int i = 0; i < 4; i++)
#pragma unroll
        for (int j = 0; j < 4; j++) acc[i][j] = (floatx4)0.0f;

    for (int k0 = 0; k0 < K; k0 += 64) {
#pragma unroll
        for (int it = 0; it < 4; it++) {
            int r0 = w * 32 + it * 8;
            int r = r0 + srow;
            gl_lds16(&A[(size_t)(row0 + r) * K + k0 + kcsrc * 8], &As[r0 * 64]);
            gl_lds16(&B[(size_t)(col0 + r) * K + k0 + kcsrc * 8], &Bs[r0 * 64]);
        }
        __syncthreads();
#pragma unroll
        for (int kk = 0; kk < 2; kk++) {
            int slot = (kk * 4 + lq) ^ (lrow & 7);
            short8 af[4], bfr[4];
#pragma unroll
            for (int i = 0; i < 4; i++)
                af[i] = *(const short8*)&As[(wr + i * 16 + lrow) * 64 + slot * 8];
#pragma unroll
            for (int j = 0; j < 4; j++)
                bfr[j] = *(const short8*)&Bs[(wc + j * 16 + lrow) * 64 + slot * 8];
#pragma unroll
            for (int i = 0; i < 4; i++)
#pragma unroll
                for (int j = 0; j < 4; j++)
                    acc[i][j] = __builtin_amdgcn_mfma_f32_16x16x32_bf16(af[i], bfr[j], acc[i][j], 0, 0, 0);
        }
        __syncthreads();
    }

    // ---- C store
#pragma unroll
    for (int i = 0; i < 4; i++)
#pragma unroll
        for (int j = 0; j < 4; j++)
#pragma unroll
            for (int r = 0; r < 4; r++) {
                int row = row0 + wr + i * 16 + lq * 4 + r;
                int col = col0 + wc + j * 16 + lrow;
                Cout[(size_t)row * Nc + col] = f2bf(acc[i][j][r]);
            }

    // ---- fused es/ed epilogue
    float asv[4], adv[4];
#pragma unroll
    for (int j = 0; j < 4; j++) {
        int colA = col0 + wc + j * 16 + lrow;
        asv[j] = a_s[colA];
        adv[j] = a_d[colA];
    }
    int hb = (col0 + wc) / C;
#pragma unroll
    for (int i = 0; i < 4; i++)
#pragma unroll
        for (int r = 0; r < 4; r++) {
            float s_h[HPW], d_h[HPW];
#pragma unroll
            for (int hh = 0; hh < HPW; hh++) { s_h[hh] = 0.f; d_h[hh] = 0.f; }
#pragma unroll
            for (int j = 0; j < 4; j++) {
                s_h[j / JPH] = fmaf(acc[i][j][r], asv[j], s_h[j / JPH]);
                d_h[j / JPH] = fmaf(acc[i][j][r], adv[j], d_h[j / JPH]);
            }
#pragma unroll
            for (int hh = 0; hh < HPW; hh++) {
#pragma unroll
                for (int off = 1; off <= 8; off <<= 1) {
                    s_h[hh] += __shfl_xor(s_h[hh], off);
                    d_h[hh] += __shfl_xor(d_h[hh], off);
                }
            }
            if (lrow == 0) {
                int row = row0 + wr + i * 16 + lq * 4 + r;
                if (row < NN) {
#pragma unroll
                    for (int hh = 0; hh < HPW; hh++) {
                        es[row * 8 + hb + hh] = s_h[hh];
                        ed[row * 8 + hb + hh] = d_h[hh];
                    }
                }
            }
        }
}

// ---------------------------------------------------------------------------
// Attention — ONE WAVE PER NODE, wave-synchronous.
// Pass 1: online softmax, stash leaky-relu logits in per-wave LDS slab.
// Fixup : convert slab in place to normalized alpha (lane head == slab head).
// Pass 2: ds_read alpha + 16B h gather, U*EPI edges in flight.
// ---------------------------------------------------------------------------
template <int C, bool ELU>
__global__ __launch_bounds__(256) void attn_wave(const short* __restrict__ h,
                                                 const float* __restrict__ es,
                                                 const float* __restrict__ ed,
                                                 const int* __restrict__ row_ptr,
                                                 const int* __restrict__ srcs,
                                                 const float* __restrict__ bias,
                                                 short* __restrict__ out) {
    constexpr int HC = NHEAD * C;
    constexpr int TPR = HC / 8;        // lanes covering one row: 64/32/16
    constexpr int EPI = 64 / TPR;      // edge groups per wave: 1/2/4
    constexpr int U = (EPI == 1) ? 4 : 2;   // unroll: U*EPI loads in flight
    __shared__ float lw[4][DEG_CAPW * NHEAD];
    int wave = threadIdx.x >> 6, lane = threadIdx.x & 63;
    float* lwW = lw[wave];
    int n = blockIdx.x * 4 + wave;     // grid = NN/4 exactly (NN%4==0)
    int start = row_ptr[n];
    int deg = row_ptr[n + 1] - start;
    int degc = deg < DEG_CAPW ? deg : DEG_CAPW;
    int hh1 = lane & 7;
    float edv = ed[n * 8 + hh1];

    // pass 1: online per-head softmax stats; stash logits (idx = k*8+head)
    float pm = -1e30f, ps = 0.f;
    for (int idx = lane; idx < deg * 8; idx += 64) {
        int s = srcs[start + (idx >> 3)];
        float e = es[s * 8 + hh1] + edv;
        e = e > 0.f ? e : 0.2f * e;
        if (idx < DEG_CAPW * 8) lwW[idx] = e;
        float mn = fmaxf(pm, e);
        ps = ps * __expf(pm - mn) + __expf(e - mn);
        pm = mn;
    }
#pragma unroll
    for (int off = 8; off <= 32; off <<= 1) {
        float mo = __shfl_xor(pm, off);
        float so = __shfl_xor(ps, off);
        float mn = fmaxf(pm, mo);
        ps = ps * __expf(pm - mn) + so * __expf(mo - mn);
        pm = mn;
    }
    float invd = 1.0f / ps;

    // fixup: slab logit -> normalized alpha (lane idx&7 == lane&7 == hh1)
    int m8 = degc * 8;
    for (int idx = lane; idx < m8; idx += 64)
        lwW[idx] = __expf(lwW[idx] - pm) * invd;
    __builtin_amdgcn_wave_barrier();
    __asm__ volatile("s_waitcnt lgkmcnt(0)" ::: "memory");

    // remap per-head state to pass-2 lane roles (for fallback only)
    int g = lane / TPR;
    int sub = lane & (TPR - 1);
    int c0 = sub * 8;
    int hh = c0 / C;                   // head of this lane's channel chunk
    float mh3 = __shfl(pm, hh);
    float iv3 = __shfl(invd, hh);
    float ed3 = __shfl(edv, hh);

    float acc[8];
#pragma unroll
    for (int j = 0; j < 8; j++) acc[j] = 0.f;

    // pass 2: U*EPI edges in flight
    int k = g;
    for (; k + (U - 1) * EPI < degc; k += U * EPI) {
        int ss[U];
        float ww[U];
#pragma unroll
        for (int u = 0; u < U; u++) {
            ss[u] = srcs[start + k + u * EPI];
            ww[u] = lwW[(k + u * EPI) * 8 + hh];
        }
        uintx4 hv[U];
#pragma unroll
        for (int u = 0; u < U; u++)
            hv[u] = *(const uintx4*)&h[(size_t)ss[u] * HC + c0];
#pragma unroll
        for (int u = 0; u < U; u++) {
#pragma unroll
            for (int j = 0; j < 4; j++) {
                acc[2 * j]     = fmaf(ww[u], bf2f_lo(hv[u][j]), acc[2 * j]);
                acc[2 * j + 1] = fmaf(ww[u], bf2f_hi(hv[u][j]), acc[2 * j + 1]);
            }
        }
    }
    for (; k < degc; k += EPI) {
        int s = srcs[start + k];
        float wv = lwW[k * 8 + hh];
        uintx4 hv = *(const uintx4*)&h[(size_t)s * HC + c0];
#pragma unroll
        for (int j = 0; j < 4; j++) {
            acc[2 * j]     = fmaf(wv, bf2f_lo(hv[j]), acc[2 * j]);
            acc[2 * j + 1] = fmaf(wv, bf2f_hi(hv[j]), acc[2 * j + 1]);
        }
    }
    if (deg > DEG_CAPW) {              // robust fallback (not taken here)
        for (int kk = DEG_CAPW + g; kk < deg; kk += EPI) {
            int s = srcs[start + kk];
            float e = es[s * 8 + hh] + ed3;
            e = e > 0.f ? e : 0.2f * e;
            float wv = __expf(e - mh3) * iv3;
            uintx4 hv = *(const uintx4*)&h[(size_t)s * HC + c0];
#pragma unroll
            for (int j = 0; j < 4; j++) {
                acc[2 * j]     = fmaf(wv, bf2f_lo(hv[j]), acc[2 * j]);
                acc[2 * j + 1] = fmaf(wv, bf2f_hi(hv[j]), acc[2 * j + 1]);
            }
        }
    }
    if (EPI >= 2) {
#pragma unroll
        for (int j = 0; j < 8; j++) acc[j] += __shfl_xor(acc[j], 32);
    }
    if (EPI == 4) {
#pragma unroll
        for (int j = 0; j < 8; j++) acc[j] += __shfl_xor(acc[j], 16);
    }
    if (lane < TPR) {
        floatx4 b0 = *(const floatx4*)&bias[c0];
        floatx4 b1 = *(const floatx4*)&bias[c0 + 4];
        float bb[8] = {b0[0], b0[1], b0[2], b0[3], b1[0], b1[1], b1[2], b1[3]};
        unsigned pk[4];
#pragma unroll
        for (int j = 0; j < 4; j++) {
            float o0 = acc[2 * j] + bb[2 * j];
            float o1 = acc[2 * j + 1] + bb[2 * j + 1];
            if (ELU) {
                o0 = o0 > 0.f ? o0 : (__expf(o0) - 1.0f);
                o1 = o1 > 0.f ? o1 : (__expf(o1) - 1.0f);
            }
            pk[j] = ((unsigned)(unsigned short)f2bf(o0)) |
                    (((unsigned)(unsigned short)f2bf(o1)) << 16);
        }
        *(uintx4*)&out[(size_t)n * HC + c0] = *(uintx4*)pk;
    }
}

// ---------------------------------------------------------------------------
// Global mean pool: 64 graphs x 8 feature-chunks of 64; 4 row stripes/block.
// ---------------------------------------------------------------------------
__global__ __launch_bounds__(256) void pool_kernel(const short* __restrict__ h,
                                                   const int* __restrict__ batch,
                                                   float* __restrict__ gout) {
    __shared__ float red[256];
    int g = blockIdx.x >> 3;
    int fc = (blockIdx.x & 7) * 64;
    int lo = 0, hi = NN;
    while (lo < hi) { int mid = (lo + hi) >> 1; if (batch[mid] < g) lo = mid + 1; else hi = mid; }
    int s = lo;
    lo = 0; hi = NN;
    while (lo < hi) { int mid = (lo + hi) >> 1; if (batch[mid] < g + 1) lo = mid + 1; else hi = mid; }
    int e = lo;
    int t = threadIdx.x;
    int f = t & 63, stripe = t >> 6;
    float a = 0.f;
    for (int r = s + stripe; r < e; r += 4)
        a += bf2f(h[(size_t)r * 512 + fc + f]);
    red[t] = a;
    __syncthreads();
    if (t < 128) red[t] += red[t + 128];
    __syncthreads();
    if (t < 64) {
        float inv = 1.0f / fmaxf((float)(e - s), 1.0f);
        gout[g * 512 + fc + t] = (red[t] + red[t + 64]) * inv;
    }
}

// ---------------------------------------------------------------------------
// Final MLP: [64,512] -> elu(@lw1^T+lb1) -> @lw2^T+lb2 -> [64,2]
// ---------------------------------------------------------------------------
__global__ __launch_bounds__(64) void mlp_kernel(const float* __restrict__ g,
                                                 const float* __restrict__ lw1,
                                                 const float* __restrict__ lb1,
                                                 const float* __restrict__ lw2,
                                                 const float* __restrict__ lb2,
                                                 float* __restrict__ outp) {
    __shared__ float gv[512];
    __shared__ float y1[32];
    int b = blockIdx.x, t = threadIdx.x;
    for (int i = t; i < 512; i += 64) gv[i] = g[b * 512 + i];
    __syncthreads();
    if (t < 32) {
        float a = lb1[t];
        for (int k = 0; k < 512; k++) a = fmaf(gv[k], lw1[t * 512 + k], a);
        y1[t] = a > 0.f ? a : (__expf(a) - 1.0f);
    }
    __syncthreads();
    if (t < 2) {
        float a = lb2[t];
        for (int k = 0; k < 32; k++) a = fmaf(y1[k], lw2[t * 32 + k], a);
        outp[b * 2 + t] = a;
    }
}

// ---------------------------------------------------------------------------
// Launch
// ---------------------------------------------------------------------------
extern "C" void kernel_launch(void* const* d_in, const int* in_sizes, int n_in,
                              void* d_out, int out_size, void* d_ws, size_t ws_size,
                              hipStream_t stream) {
    (void)in_sizes; (void)n_in; (void)out_size; (void)ws_size;
    const float* x     = (const float*)d_in[0];
    const int*   ei    = (const int*)d_in[1];
    const int*   batch = (const int*)d_in[2];
    const float* W[4]  = {(const float*)d_in[3], (const float*)d_in[7],
                          (const float*)d_in[11], (const float*)d_in[15]};
    const float* As_[4] = {(const float*)d_in[4], (const float*)d_in[8],
                           (const float*)d_in[12], (const float*)d_in[16]};
    const float* Ad_[4] = {(const float*)d_in[5], (const float*)d_in[9],
                           (const float*)d_in[13], (const float*)d_in[17]};
    const float* Bi[4]  = {(const float*)d_in[6], (const float*)d_in[10],
                           (const float*)d_in[14], (const float*)d_in[18]};
    const float* lw1 = (const float*)d_in[19];
    const float* lb1 = (const float*)d_in[20];
    const float* lw2 = (const float*)d_in[21];
    const float* lb2 = (const float*)d_in[22];
    float* out = (float*)d_out;

    // workspace layout (bf16 buffers as short)
    short* Ab = (short*)d_ws;                      // [MPAD*512] activations
    short* Hb = Ab + (size_t)MPAD * 512;           // [MPAD*512] h = act @ W^T
    short* Wb = Hb + (size_t)MPAD * 512;           // bf16 weights
    short* Wb_[4] = {Wb, Wb + 65536, Wb + 196608, Wb + 229376};
    const int wsz[4] = {65536, 131072, 32768, 65536};
    float* esb  = (float*)(Wb + 294912);           // [NN*8]
    float* edb  = esb + NN * NHEAD;                // [NN*8]
    float* gbuf = edb + NN * NHEAD;                // [64*512]
    int* row_ptr = (int*)(gbuf + NGR * 512);       // [NN+1]
    int* cursor  = row_ptr + (NN + 1);             // [NN+1]
    int* srcs    = cursor + (NN + 1);              // [NEP]
    int* bsum    = srcs + NEP;                     // [64]

    const int nblk = (NN + 1023) / 1024;           // 49

    // ---- CSR build (shared by all 4 layers)
    hipMemsetAsync(cursor, 0, NN * sizeof(int), stream);
    count_deg<<<(NEP + 255) / 256, 256, 0, stream>>>(ei, cursor);
    scan_local<<<nblk, 1024, 0, stream>>>(cursor, row_ptr, bsum, NN);
    scan_bsum<<<1, 64, 0, stream>>>(bsum, nblk);
    scan_add<<<(NN + 256) / 256, 256, 0, stream>>>(row_ptr, cursor, bsum, NN, nblk);
    scatter_edges<<<(NEP + 255) / 256, 256, 0, stream>>>(ei, cursor, srcs);

    // ---- bf16 conversions
    conv_x_pad4<<<(MPAD * 32 + 255) / 256, 256, 0, stream>>>(x, Ab);
    for (int i = 0; i < 4; i++)
        conv_f2bf<<<(wsz[i] + 255) / 256, 256, 0, stream>>>(W[i], Wb_[i], wsz[i]);

    const int rowTiles = MPAD / 128;               // 391
    const int ag = NN / 4;                         // 12500 blocks, 4 nodes each

    // ---- layer 1: 128 -> 512 (C=64), ELU
    gemm_bf<64><<<rowTiles * 4, 256, 0, stream>>>(Ab, Wb_[0], Hb, As_[0], Ad_[0], esb, edb, 128);
    attn_wave<64, true><<<ag, 256, 0, stream>>>(Hb, esb, edb, row_ptr, srcs, Bi[0], Ab);

    // ---- layer 2: 512 -> 256 (C=32), ELU
    gemm_bf<32><<<rowTiles * 2, 256, 0, stream>>>(Ab, Wb_[1], Hb, As_[1], Ad_[1], esb, edb, 512);
    attn_wave<32, true><<<ag, 256, 0, stream>>>(Hb, esb, edb, row_ptr, srcs, Bi[1], Ab);

    // ---- layer 3: 256 -> 128 (C=16), ELU
    gemm_bf<16><<<rowTiles * 1, 256, 0, stream>>>(Ab, Wb_[2], Hb, As_[2], Ad_[2], esb, edb, 256);
    attn_wave<16, true><<<ag, 256, 0, stream>>>(Hb, esb, edb, row_ptr, srcs, Bi[2], Ab);

    // ---- layer 4: 128 -> 512 (C=64), no ELU
    gemm_bf<64><<<rowTiles * 4, 256, 0, stream>>>(Ab, Wb_[3], Hb, As_[3], Ad_[3], esb, edb, 128);
    attn_wave<64, false><<<ag, 256, 0, stream>>>(Hb, esb, edb, row_ptr, srcs, Bi[3], Ab);

    // ---- pool + MLP
    pool_kernel<<<NGR * 8, 256, 0, stream>>>(Ab, batch, gbuf);
    mlp_kernel<<<NGR, 64, 0, stream>>>(gbuf, lw1, lb1, lw2, lb2, out);
}